// Round 1
// baseline (1374.471 us; speedup 1.0000x reference)
//
#include <hip/hip_runtime.h>
#include <math.h>

#define NT   16384
#define DIM  1024
#define HID  2048
#define NE   16
#define CAP  8192

typedef __attribute__((ext_vector_type(4))) short short4v;
typedef __attribute__((ext_vector_type(8))) short short8v;
typedef __attribute__((ext_vector_type(4))) float f32x4;

__device__ __forceinline__ short f2bf(float f){
  union { float f; unsigned u; } c; c.f = f;
  unsigned r = (c.u + 0x7fffu + ((c.u >> 16) & 1u)) >> 16;
  return (short)r;
}
__device__ __forceinline__ float bf2f(short s){
  union { unsigned u; float f; } c; c.u = ((unsigned)(unsigned short)s) << 16;
  return c.f;
}

// ---------------- router: logits -> softmax -> top2 + importance/counts ----
__global__ __launch_bounds__(256) void router_kernel(
    const float* __restrict__ x, const float* __restrict__ rw, const float* __restrict__ rb,
    int* __restrict__ tki, float* __restrict__ tkw,
    int* __restrict__ counts, float* __restrict__ importance)
{
  __shared__ short WsB[1024*20];   // bf16 router_w, stride 20 (bank-spread)
  __shared__ float Rb[16];
  int tid = threadIdx.x;
  for (int i = tid; i < 1024*16; i += 256){
    int k = i >> 4, e2 = i & 15;
    WsB[k*20 + e2] = f2bf(rw[i]);
  }
  if (tid < 16) Rb[tid] = rb[tid];
  __syncthreads();
  int wave = tid >> 6, lane = tid & 63;
  float impAcc[16]; int cntAcc[16];
#pragma unroll
  for (int e=0;e<16;e++){ impAcc[e]=0.f; cntAcc[e]=0; }
  for (int t = 0; t < 16; ++t){
    int tok = blockIdx.x*64 + wave*16 + t;
    const float* xr = x + (size_t)tok*DIM;
    float p[16];
#pragma unroll
    for (int e=0;e<16;e++) p[e]=0.f;
    for (int j = 0; j < 16; ++j){
      int k = lane + 64*j;
      float xv = xr[k];
      const short* wr0 = &WsB[k*20];
#pragma unroll
      for (int q=0;q<4;q++){
        short4v w4 = *(const short4v*)(wr0 + q*4);
        p[4*q+0] += xv * bf2f(w4[0]);
        p[4*q+1] += xv * bf2f(w4[1]);
        p[4*q+2] += xv * bf2f(w4[2]);
        p[4*q+3] += xv * bf2f(w4[3]);
      }
    }
#pragma unroll
    for (int e=0;e<16;e++){
      float v = p[e];
#pragma unroll
      for (int off=32; off>0; off>>=1) v += __shfl_xor(v, off, 64);
      p[e] = v + Rb[e];
    }
    float mx = p[0];
#pragma unroll
    for (int e=1;e<16;e++) mx = fmaxf(mx, p[e]);
    float s = 0.f;
#pragma unroll
    for (int e=0;e<16;e++){ p[e] = expf(p[e]-mx); s += p[e]; }
    float inv = 1.f/s;
#pragma unroll
    for (int e=0;e<16;e++) p[e] *= inv;
    // top-2, ties -> lower index (matches jax.lax.top_k)
    float v1=-1.f, v2=-1.f; int i1=0, i2=0;
#pragma unroll
    for (int e=0;e<16;e++){
      float pe = p[e];
      if (pe > v1){ v2=v1; i2=i1; v1=pe; i1=e; }
      else if (pe > v2){ v2=pe; i2=e; }
    }
    if (lane==0){
      tki[2*tok] = i1; tki[2*tok+1] = i2;
      tkw[2*tok] = v1; tkw[2*tok+1] = v2;
    }
#pragma unroll
    for (int e=0;e<16;e++){
      impAcc[e] += p[e];
      cntAcc[e] += (i1==e) + (i2==e);
    }
  }
  if (lane==0){
#pragma unroll
    for (int e=0;e<16;e++){
      atomicAdd(&importance[e], impAcc[e]);
      atomicAdd(&counts[e], cntAcc[e]);
    }
  }
}

// ---------------- per-expert ordered token lists (exact capacity semantics) --
__global__ __launch_bounds__(1024) void build_lists_kernel(
    const int* __restrict__ tki, const float* __restrict__ tkw,
    int* __restrict__ list, float* __restrict__ wtok, int* __restrict__ keptArr)
{
  __shared__ int sc[1024];
  int e = blockIdx.x;
  int tid = threadIdx.x;
  int base = 0;
  for (int c = 0; c < NT/1024; ++c){
    int t = c*1024 + tid;
    int i1 = tki[2*t], i2 = tki[2*t+1];
    int mask = (i1==e || i2==e) ? 1 : 0;
    sc[tid] = mask;
    __syncthreads();
    for (int off=1; off<1024; off<<=1){
      int v = (tid>=off) ? sc[tid-off] : 0;
      __syncthreads();
      sc[tid] += v;
      __syncthreads();
    }
    int rank = base + sc[tid] - mask;
    if (mask && rank < CAP){
      list[e*CAP + rank] = t;
      wtok[e*CAP + rank] = (i1==e) ? tkw[2*t] : tkw[2*t+1];
    }
    base += sc[1023];
    __syncthreads();
  }
  if (tid==0) keptArr[e] = min(base, CAP);
}

// ---------------- aux loss + padded row offsets -----------------------------
__global__ void finalize_kernel(const int* __restrict__ counts, const float* __restrict__ importance,
                                const int* __restrict__ keptArr, int* __restrict__ padOff,
                                float* __restrict__ auxOut)
{
  if (threadIdx.x == 0 && blockIdx.x == 0){
    float bal = 0.f, il = 0.f;
    int po = 0;
    padOff[0] = 0;
    for (int e=0;e<16;e++){
      float im = importance[e];
      float cf = (float)counts[e];
      bal += (im * (1.f/NT)) * (cf * (1.f/NT));
      il  += im*im;
      po  += ((keptArr[e] + 127) >> 7) << 7;
      padOff[e+1] = po;
    }
    auxOut[0] = bal * 16.f + il * (1.f/16.f);
  }
}

// ---------------- GEMM1: hid = gelu(gather(x) @ w1[e] + b1[e]) --------------
__global__ __launch_bounds__(256) void gemm1_kernel(
    const float* __restrict__ x, const float* __restrict__ w1, const float* __restrict__ b1,
    const int* __restrict__ list, const int* __restrict__ keptArr, const int* __restrict__ padOff,
    short* __restrict__ hid)
{
  int e = blockIdx.z;
  int kept = keptArr[e];
  int mt = blockIdx.y;
  if (mt*128 >= kept) return;
  int n0 = blockIdx.x * 128;

  __shared__ short As[128*32];   // [m][k]
  __shared__ short Bs[128*48];   // [n][k], stride 48 -> aligned b128, bank-spread

  const float* Wg  = w1 + (size_t)e*DIM*HID;
  const int*   lst = list + e*CAP;
  int tid = threadIdx.x;
  int lane = tid & 63;
  int wv = tid >> 6, wr = wv >> 1, wc = wv & 1;

  f32x4 zero = {0.f,0.f,0.f,0.f};
  f32x4 acc[4][4];
#pragma unroll
  for (int i=0;i<4;i++)
#pragma unroll
    for (int j=0;j<4;j++) acc[i][j] = zero;

  int nB = tid & 127, kh = tid >> 7;
  for (int kt = 0; kt < DIM/32; ++kt){
    int k0 = kt*32;
    __syncthreads();
    // stage A: gather token rows, fp32 -> bf16
#pragma unroll
    for (int it=0; it<4; ++it){
      int idx = tid + 256*it;
      int r = idx >> 3, c4 = idx & 7;
      int gm = mt*128 + r;
      float4 xv = make_float4(0.f,0.f,0.f,0.f);
      if (gm < kept){
        int tok = lst[gm];
        xv = *(const float4*)(x + (size_t)tok*DIM + k0 + c4*4);
      }
      short4v h4;
      h4[0]=f2bf(xv.x); h4[1]=f2bf(xv.y); h4[2]=f2bf(xv.z); h4[3]=f2bf(xv.w);
      *(short4v*)(As + r*32 + c4*4) = h4;
    }
    // stage B transposed: Bs[n][k] <- w1[k][n]
#pragma unroll
    for (int kc=0;kc<4;kc++){
      int kb = kh*16 + kc*4;
      short4v u;
#pragma unroll
      for (int jj=0;jj<4;jj++)
        u[jj] = f2bf(Wg[(size_t)(k0+kb+jj)*HID + n0 + nB]);
      *(short4v*)(Bs + nB*48 + kb) = u;
    }
    __syncthreads();
    int row = lane & 15, kq = lane >> 4;
    short8v a[4], b[4];
#pragma unroll
    for (int i=0;i<4;i++)
      a[i] = *(const short8v*)(As + (wr*64 + i*16 + row)*32 + kq*8);
#pragma unroll
    for (int i=0;i<4;i++)
      b[i] = *(const short8v*)(Bs + (wc*64 + i*16 + row)*48 + kq*8);
#pragma unroll
    for (int i=0;i<4;i++)
#pragma unroll
      for (int j=0;j<4;j++)
        acc[i][j] = __builtin_amdgcn_mfma_f32_16x16x32_bf16(a[i], b[j], acc[i][j], 0, 0, 0);
  }
  const float* b1e = b1 + (size_t)e*HID;
  int rowBase = padOff[e] + mt*128 + wr*64;
  int rg = lane >> 4, cl = lane & 15;
#pragma unroll
  for (int i=0;i<4;i++){
#pragma unroll
    for (int j=0;j<4;j++){
      int h = n0 + wc*64 + j*16 + cl;
      float bias = b1e[h];
#pragma unroll
      for (int r=0;r<4;r++){
        float v = acc[i][j][r] + bias;
        v = 0.5f*v*(1.f + erff(v*0.70710678118654752f));   // exact (erf) GELU
        hid[(size_t)(rowBase + i*16 + rg*4 + r)*HID + h] = f2bf(v);
      }
    }
  }
}

// ---------------- GEMM2: y[tok] += (hid @ w2[e] + b2[e]) * w_tok ------------
__global__ __launch_bounds__(256) void gemm2_kernel(
    const short* __restrict__ hid, const float* __restrict__ w2, const float* __restrict__ b2,
    const int* __restrict__ list, const float* __restrict__ wtok,
    const int* __restrict__ keptArr, const int* __restrict__ padOff,
    float* __restrict__ y)
{
  int e = blockIdx.z;
  int kept = keptArr[e];
  int mt = blockIdx.y;
  if (mt*128 >= kept) return;
  int n0 = blockIdx.x * 128;

  __shared__ short As[128*32];
  __shared__ short Bs[128*48];

  const float* Wg = w2 + (size_t)e*HID*DIM;
  const short* hb = hid + (size_t)padOff[e]*HID;
  int tid = threadIdx.x;
  int lane = tid & 63;
  int wv = tid >> 6, wr = wv >> 1, wc = wv & 1;

  f32x4 zero = {0.f,0.f,0.f,0.f};
  f32x4 acc[4][4];
#pragma unroll
  for (int i=0;i<4;i++)
#pragma unroll
    for (int j=0;j<4;j++) acc[i][j] = zero;

  int nB = tid & 127, kh = tid >> 7;
  for (int kt = 0; kt < HID/32; ++kt){
    int k0 = kt*32;
    __syncthreads();
#pragma unroll
    for (int it=0; it<4; ++it){
      int idx = tid + 256*it;
      int r = idx >> 3, c4 = idx & 7;
      *(short4v*)(As + r*32 + c4*4) =
        *(const short4v*)(hb + (size_t)(mt*128 + r)*HID + k0 + c4*4);
    }
#pragma unroll
    for (int kc=0;kc<4;kc++){
      int kb = kh*16 + kc*4;
      short4v u;
#pragma unroll
      for (int jj=0;jj<4;jj++)
        u[jj] = f2bf(Wg[(size_t)(k0+kb+jj)*DIM + n0 + nB]);
      *(short4v*)(Bs + nB*48 + kb) = u;
    }
    __syncthreads();
    int row = lane & 15, kq = lane >> 4;
    short8v a[4], b[4];
#pragma unroll
    for (int i=0;i<4;i++)
      a[i] = *(const short8v*)(As + (wr*64 + i*16 + row)*32 + kq*8);
#pragma unroll
    for (int i=0;i<4;i++)
      b[i] = *(const short8v*)(Bs + (wc*64 + i*16 + row)*48 + kq*8);
#pragma unroll
    for (int i=0;i<4;i++)
#pragma unroll
      for (int j=0;j<4;j++)
        acc[i][j] = __builtin_amdgcn_mfma_f32_16x16x32_bf16(a[i], b[j], acc[i][j], 0, 0, 0);
  }
  const float* b2e = b2 + (size_t)e*DIM;
  const int*   lst = list + e*CAP;
  const float* wt  = wtok + e*CAP;
  int rg = lane >> 4, cl = lane & 15;
#pragma unroll
  for (int i=0;i<4;i++){
#pragma unroll
    for (int r=0;r<4;r++){
      int m = mt*128 + wr*64 + i*16 + rg*4 + r;
      if (m < kept){
        int tok = lst[m];
        float w = wt[m];
#pragma unroll
        for (int j=0;j<4;j++){
          int n = n0 + wc*64 + j*16 + cl;
          float v = acc[i][j][r] + b2e[n];
          atomicAdd(y + (size_t)tok*DIM + n, v*w);
        }
      }
    }
  }
}

// ---------------- launch ----------------------------------------------------
extern "C" void kernel_launch(void* const* d_in, const int* in_sizes, int n_in,
                              void* d_out, int out_size, void* d_ws, size_t ws_size,
                              hipStream_t stream)
{
  (void)in_sizes; (void)n_in; (void)ws_size;
  const float* x  = (const float*)d_in[0];
  const float* rw = (const float*)d_in[1];
  const float* rb = (const float*)d_in[2];
  const float* w1 = (const float*)d_in[3];
  const float* b1 = (const float*)d_in[4];
  const float* w2 = (const float*)d_in[5];
  const float* b2 = (const float*)d_in[6];
  float* y = (float*)d_out;

  // workspace layout (total ~138.3 MiB):
  //   [0..63]    counts[16]        [64..127] kept[16]
  //   [128..191] importance[16]    [192..]   pad_off[17]
  char* ws = (char*)d_ws;
  int*   counts = (int*)(ws + 0);
  int*   kept   = (int*)(ws + 64);
  float* imp    = (float*)(ws + 128);
  int*   padoff = (int*)(ws + 192);
  int*   list   = (int*)(ws + 4096);                         // 16*8192*4 = 512 KiB
  float* wtok   = (float*)(ws + 4096 + 524288);              // 512 KiB
  int*   tki    = (int*)(ws + 4096 + 2*524288);              // 128 KiB
  float* tkw    = (float*)(ws + 4096 + 2*524288 + 131072);   // 128 KiB
  short* hid    = (short*)(ws + 4096 + 2*524288 + 2*131072); // <=35072 rows * 2048 bf16

  hipMemsetAsync(ws, 0, 4096, stream);                       // counts/kept/imp/padoff
  hipMemsetAsync(d_out, 0, (size_t)out_size * sizeof(float), stream);

  router_kernel<<<256, 256, 0, stream>>>(x, rw, rb, tki, tkw, counts, imp);
  build_lists_kernel<<<16, 1024, 0, stream>>>(tki, tkw, list, wtok, kept);
  finalize_kernel<<<1, 64, 0, stream>>>(counts, imp, kept, padoff, y + (size_t)NT*DIM);
  gemm1_kernel<<<dim3(16, 64, 16), 256, 0, stream>>>(x, w1, b1, list, kept, padoff, hid);
  gemm2_kernel<<<dim3(8, 64, 16), 256, 0, stream>>>(hid, w2, b2, list, wtok, kept, padoff, y);
}

// Round 2
// 954.286 us; speedup vs baseline: 1.4403x; 1.4403x over previous
//
#include <hip/hip_runtime.h>
#include <math.h>

#define NT   16384
#define DIM  1024
#define HID  2048
#define NE   16
#define CAP  8192
#define MAXROWS 34816   // sum(kept) <= 32768, + 16*127 padding

typedef __attribute__((ext_vector_type(4))) short short4v;
typedef __attribute__((ext_vector_type(4))) float f32x4;
typedef long long i64;

__device__ __forceinline__ short f2bf(float f){
  union { float f; unsigned u; } c; c.f = f;
  unsigned r = (c.u + 0x7fffu + ((c.u >> 16) & 1u)) >> 16;
  return (short)r;
}
__device__ __forceinline__ float bf2f(short s){
  union { unsigned u; float f; } c; c.u = ((unsigned)(unsigned short)s) << 16;
  return c.f;
}
__device__ __forceinline__ unsigned pk4fp8(float a, float b, float c, float d){
  int lo  = __builtin_amdgcn_cvt_pk_fp8_f32(a, b, 0, false);
  int all = __builtin_amdgcn_cvt_pk_fp8_f32(c, d, lo, true);
  return (unsigned)all;
}
__device__ __forceinline__ unsigned char fp8one(float a){
  return (unsigned char)(__builtin_amdgcn_cvt_pk_fp8_f32(a, a, 0, false) & 0xff);
}

#define GLOAD16(g, l) __builtin_amdgcn_global_load_lds( \
    (const __attribute__((address_space(1))) void*)(g), \
    (__attribute__((address_space(3))) void*)(l), 16, 0, 0)

// ---------------- x -> fp8 ---------------------------------------------------
__global__ __launch_bounds__(256) void convx_kernel(const float* __restrict__ x,
                                                    unsigned* __restrict__ x8){
  int idx = blockIdx.x*256 + threadIdx.x;        // one uint = 4 fp8
  float4 v = ((const float4*)x)[idx];
  x8[idx] = pk4fp8(v.x, v.y, v.z, v.w);
}

// ---------------- w [E][K][N] f32 -> wt8 [E][N][K] fp8 (x scale) ------------
__global__ __launch_bounds__(256) void prepw_kernel(const float* __restrict__ w,
                                                    unsigned char* __restrict__ wt8,
                                                    int K, int N, float scale){
  __shared__ float T[64][65];
  int e = blockIdx.z;
  int n0 = blockIdx.x*64, k0 = blockIdx.y*64;
  const float* we = w + (size_t)e*K*N;
  unsigned char* oe = wt8 + (size_t)e*K*N;
  int tid = threadIdx.x;
  int rr = tid >> 4, c4 = tid & 15;
#pragma unroll
  for (int p = 0; p < 4; ++p){
    int r = rr + p*16;
    float4 v = *(const float4*)(we + (size_t)(k0 + r)*N + n0 + c4*4);
    T[r][c4*4+0] = v.x*scale; T[r][c4*4+1] = v.y*scale;
    T[r][c4*4+2] = v.z*scale; T[r][c4*4+3] = v.w*scale;
  }
  __syncthreads();
#pragma unroll
  for (int p = 0; p < 4; ++p){
    int n = rr + p*16;
    unsigned u = pk4fp8(T[c4*4+0][n], T[c4*4+1][n], T[c4*4+2][n], T[c4*4+3][n]);
    *(unsigned*)(oe + (size_t)(n0 + n)*K + k0 + c4*4) = u;
  }
}

// ---------------- router: logits -> softmax -> top2 + importance/counts ----
__global__ __launch_bounds__(256) void router_kernel(
    const float* __restrict__ x, const float* __restrict__ rw, const float* __restrict__ rb,
    int* __restrict__ tki, float* __restrict__ tkw,
    int* __restrict__ counts, float* __restrict__ importance)
{
  __shared__ short WsB[1024*20];
  __shared__ float Rb[16];
  int tid = threadIdx.x;
  for (int i = tid; i < 1024*16; i += 256){
    int k = i >> 4, e2 = i & 15;
    WsB[k*20 + e2] = f2bf(rw[i]);
  }
  if (tid < 16) Rb[tid] = rb[tid];
  __syncthreads();
  int wave = tid >> 6, lane = tid & 63;
  float impAcc[16]; int cntAcc[16];
#pragma unroll
  for (int e=0;e<16;e++){ impAcc[e]=0.f; cntAcc[e]=0; }
  for (int t = 0; t < 16; ++t){
    int tok = blockIdx.x*64 + wave*16 + t;
    const float* xr = x + (size_t)tok*DIM;
    float p[16];
#pragma unroll
    for (int e=0;e<16;e++) p[e]=0.f;
    for (int j = 0; j < 16; ++j){
      int k = lane + 64*j;
      float xv = xr[k];
      const short* wr0 = &WsB[k*20];
#pragma unroll
      for (int q=0;q<4;q++){
        short4v w4 = *(const short4v*)(wr0 + q*4);
        p[4*q+0] += xv * bf2f(w4[0]);
        p[4*q+1] += xv * bf2f(w4[1]);
        p[4*q+2] += xv * bf2f(w4[2]);
        p[4*q+3] += xv * bf2f(w4[3]);
      }
    }
#pragma unroll
    for (int e=0;e<16;e++){
      float v = p[e];
#pragma unroll
      for (int off=32; off>0; off>>=1) v += __shfl_xor(v, off, 64);
      p[e] = v + Rb[e];
    }
    float mx = p[0];
#pragma unroll
    for (int e=1;e<16;e++) mx = fmaxf(mx, p[e]);
    float s = 0.f;
#pragma unroll
    for (int e=0;e<16;e++){ p[e] = expf(p[e]-mx); s += p[e]; }
    float inv = 1.f/s;
#pragma unroll
    for (int e=0;e<16;e++) p[e] *= inv;
    float v1=-1.f, v2=-1.f; int i1=0, i2=0;
#pragma unroll
    for (int e=0;e<16;e++){
      float pe = p[e];
      if (pe > v1){ v2=v1; i2=i1; v1=pe; i1=e; }
      else if (pe > v2){ v2=pe; i2=e; }
    }
    if (lane==0){
      tki[2*tok] = i1; tki[2*tok+1] = i2;
      tkw[2*tok] = v1; tkw[2*tok+1] = v2;
    }
#pragma unroll
    for (int e=0;e<16;e++){
      impAcc[e] += p[e];
      cntAcc[e] += (i1==e) + (i2==e);
    }
  }
  if (lane==0){
#pragma unroll
    for (int e=0;e<16;e++){
      atomicAdd(&importance[e], impAcc[e]);
      atomicAdd(&counts[e], cntAcc[e]);
    }
  }
}

// ---------------- per-expert ordered token lists ----------------------------
__global__ __launch_bounds__(1024) void build_lists_kernel(
    const int* __restrict__ tki, const float* __restrict__ tkw,
    int* __restrict__ list, float* __restrict__ wtok, int* __restrict__ keptArr)
{
  __shared__ int sc[1024];
  int e = blockIdx.x;
  int tid = threadIdx.x;
  int base = 0;
  for (int c = 0; c < NT/1024; ++c){
    int t = c*1024 + tid;
    int i1 = tki[2*t], i2 = tki[2*t+1];
    int mask = (i1==e || i2==e) ? 1 : 0;
    sc[tid] = mask;
    __syncthreads();
    for (int off=1; off<1024; off<<=1){
      int v = (tid>=off) ? sc[tid-off] : 0;
      __syncthreads();
      sc[tid] += v;
      __syncthreads();
    }
    int rank = base + sc[tid] - mask;
    if (mask && rank < CAP){
      list[e*CAP + rank] = t;
      wtok[e*CAP + rank] = (i1==e) ? tkw[2*t] : tkw[2*t+1];
    }
    base += sc[1023];
    __syncthreads();
  }
  if (tid==0) keptArr[e] = min(base, CAP);
}

// ---------------- aux loss + padded row offsets -----------------------------
__global__ void finalize_kernel(const int* __restrict__ counts, const float* __restrict__ importance,
                                const int* __restrict__ keptArr, int* __restrict__ padOff,
                                float* __restrict__ auxOut)
{
  if (threadIdx.x == 0 && blockIdx.x == 0){
    float bal = 0.f, il = 0.f;
    int po = 0;
    padOff[0] = 0;
    for (int e=0;e<16;e++){
      float im = importance[e];
      float cf = (float)counts[e];
      bal += (im * (1.f/NT)) * (cf * (1.f/NT));
      il  += im*im;
      po  += ((keptArr[e] + 127) >> 7) << 7;
      padOff[e+1] = po;
    }
    auxOut[0] = bal * 16.f + il * (1.f/16.f);
  }
}

// ---------------- GEMM1: hid8 = gelu(gather(x8) @ w1t8^T /16 + b1) ----------
__global__ __launch_bounds__(256) void gemm1_kernel(
    const unsigned char* __restrict__ x8, const unsigned char* __restrict__ w1t8,
    const float* __restrict__ b1,
    const int* __restrict__ list, const int* __restrict__ keptArr, const int* __restrict__ padOff,
    unsigned char* __restrict__ hid8)
{
  int e = blockIdx.z;
  int kept = keptArr[e];
  int mt = blockIdx.y;
  if (mt*128 >= kept) return;
  int n0 = blockIdx.x * 128;

  __shared__ unsigned char As[128*64];   // [row][k] fp8, 16B-unit XOR swizzle
  __shared__ unsigned char Bs[128*64];   // [n][k]  fp8, same swizzle

  const unsigned char* Wg = w1t8 + (size_t)e*DIM*HID;
  const int* lst = list + e*CAP;
  int tid = threadIdx.x;
  int lane = tid & 63;
  int wv = tid >> 6, wr = wv >> 1, wc = wv & 1;

  int srow = tid >> 2, su = tid & 3;
  const unsigned char* srcA[2];
  const unsigned char* srcB[2];
#pragma unroll
  for (int i=0;i<2;i++){
    int row = i*64 + srow;
    int s2 = (row >> 2) & 3;
    int gm = mt*128 + row;
    int tok = lst[min(gm, kept-1)];
    srcA[i] = x8 + (size_t)tok*DIM + ((su ^ s2) << 4);
    srcB[i] = Wg + (size_t)(n0 + row)*DIM + ((su ^ s2) << 4);
  }

  f32x4 zero = {0.f,0.f,0.f,0.f};
  f32x4 acc[4][4];
#pragma unroll
  for (int i=0;i<4;i++)
#pragma unroll
    for (int j=0;j<4;j++) acc[i][j] = zero;

  int row = lane & 15, kq = lane >> 4;
  int s2r = (row >> 2) & 3;
  int kqh = kq >> 1, kql = (kq & 1) << 3;

  for (int kt = 0; kt < DIM/64; ++kt){
    __syncthreads();
    GLOAD16(srcA[0], As + tid*16);
    GLOAD16(srcA[1], As + 4096 + tid*16);
    GLOAD16(srcB[0], Bs + tid*16);
    GLOAD16(srcB[1], Bs + 4096 + tid*16);
    srcA[0]+=64; srcA[1]+=64; srcB[0]+=64; srcB[1]+=64;
    __syncthreads();
#pragma unroll
    for (int kk=0;kk<2;kk++){
      i64 a[4], b[4];
#pragma unroll
      for (int i=0;i<4;i++)
        a[i] = *(const i64*)(As + (wr*64 + i*16 + row)*64 + (((kk*2 + kqh) ^ s2r) << 4) + kql);
#pragma unroll
      for (int j=0;j<4;j++)
        b[j] = *(const i64*)(Bs + (wc*64 + j*16 + row)*64 + (((kk*2 + kqh) ^ s2r) << 4) + kql);
#pragma unroll
      for (int i=0;i<4;i++)
#pragma unroll
        for (int j=0;j<4;j++)
          acc[i][j] = __builtin_amdgcn_mfma_f32_16x16x32_fp8_fp8(a[i], b[j], acc[i][j], 0, 0, 0);
    }
  }
  const float* b1e = b1 + (size_t)e*HID;
  int rowBase = padOff[e] + mt*128 + wr*64;
  int rg = lane >> 4, cl = lane & 15;
#pragma unroll
  for (int i=0;i<4;i++){
#pragma unroll
    for (int j=0;j<4;j++){
      int h = n0 + wc*64 + j*16 + cl;
      float bias = b1e[h];
#pragma unroll
      for (int r=0;r<4;r++){
        float v = acc[i][j][r]*(1.f/16.f) + bias;
        float u = 0.7978845608f*(v + 0.044715f*v*v*v);   // tanh-approx GELU
        float t2 = __expf(2.f*u);
        float g = 0.5f*v*(1.f + (t2-1.f)/(t2+1.f));
        hid8[(size_t)(rowBase + i*16 + rg*4 + r)*HID + h] = fp8one(g);
      }
    }
  }
}

// ---------------- GEMM2: y[tok] += (hid8 @ w2t8^T /16 + b2) * w_tok ---------
__global__ __launch_bounds__(256) void gemm2_kernel(
    const unsigned char* __restrict__ hid8, const unsigned char* __restrict__ w2t8,
    const float* __restrict__ b2,
    const int* __restrict__ list, const float* __restrict__ wtok,
    const int* __restrict__ keptArr, const int* __restrict__ padOff,
    float* __restrict__ y)
{
  int e = blockIdx.z;
  int kept = keptArr[e];
  int mt = blockIdx.y;
  if (mt*128 >= kept) return;
  int n0 = blockIdx.x * 128;

  __shared__ unsigned char As[128*64];
  __shared__ unsigned char Bs[128*64];

  const unsigned char* Wg = w2t8 + (size_t)e*HID*DIM;
  const unsigned char* hb = hid8 + (size_t)(padOff[e] + mt*128)*HID;
  int tid = threadIdx.x;
  int lane = tid & 63;
  int wv = tid >> 6, wr = wv >> 1, wc = wv & 1;

  int srow = tid >> 2, su = tid & 3;
  const unsigned char* srcA[2];
  const unsigned char* srcB[2];
#pragma unroll
  for (int i=0;i<2;i++){
    int row = i*64 + srow;
    int s2 = (row >> 2) & 3;
    srcA[i] = hb + (size_t)row*HID + ((su ^ s2) << 4);
    srcB[i] = Wg + (size_t)(n0 + row)*HID + ((su ^ s2) << 4);
  }

  f32x4 zero = {0.f,0.f,0.f,0.f};
  f32x4 acc[4][4];
#pragma unroll
  for (int i=0;i<4;i++)
#pragma unroll
    for (int j=0;j<4;j++) acc[i][j] = zero;

  int row = lane & 15, kq = lane >> 4;
  int s2r = (row >> 2) & 3;
  int kqh = kq >> 1, kql = (kq & 1) << 3;

  for (int kt = 0; kt < HID/64; ++kt){
    __syncthreads();
    GLOAD16(srcA[0], As + tid*16);
    GLOAD16(srcA[1], As + 4096 + tid*16);
    GLOAD16(srcB[0], Bs + tid*16);
    GLOAD16(srcB[1], Bs + 4096 + tid*16);
    srcA[0]+=64; srcA[1]+=64; srcB[0]+=64; srcB[1]+=64;
    __syncthreads();
#pragma unroll
    for (int kk=0;kk<2;kk++){
      i64 a[4], b[4];
#pragma unroll
      for (int i=0;i<4;i++)
        a[i] = *(const i64*)(As + (wr*64 + i*16 + row)*64 + (((kk*2 + kqh) ^ s2r) << 4) + kql);
#pragma unroll
      for (int j=0;j<4;j++)
        b[j] = *(const i64*)(Bs + (wc*64 + j*16 + row)*64 + (((kk*2 + kqh) ^ s2r) << 4) + kql);
#pragma unroll
      for (int i=0;i<4;i++)
#pragma unroll
        for (int j=0;j<4;j++)
          acc[i][j] = __builtin_amdgcn_mfma_f32_16x16x32_fp8_fp8(a[i], b[j], acc[i][j], 0, 0, 0);
    }
  }
  const float* b2e = b2 + (size_t)e*DIM;
  const int*   lst = list + e*CAP;
  const float* wt  = wtok + e*CAP;
  int rg = lane >> 4, cl = lane & 15;
#pragma unroll
  for (int i=0;i<4;i++){
#pragma unroll
    for (int r=0;r<4;r++){
      int m = mt*128 + wr*64 + i*16 + rg*4 + r;
      if (m < kept){
        int tok = lst[m];
        float w = wt[m];
#pragma unroll
        for (int j=0;j<4;j++){
          int n = n0 + wc*64 + j*16 + cl;
          float v = acc[i][j][r]*(1.f/16.f) + b2e[n];
          atomicAdd(y + (size_t)tok*DIM + n, v*w);
        }
      }
    }
  }
}

// ---------------- launch ----------------------------------------------------
extern "C" void kernel_launch(void* const* d_in, const int* in_sizes, int n_in,
                              void* d_out, int out_size, void* d_ws, size_t ws_size,
                              hipStream_t stream)
{
  (void)in_sizes; (void)n_in; (void)ws_size;
  const float* x  = (const float*)d_in[0];
  const float* rw = (const float*)d_in[1];
  const float* rb = (const float*)d_in[2];
  const float* w1 = (const float*)d_in[3];
  const float* b1 = (const float*)d_in[4];
  const float* w2 = (const float*)d_in[5];
  const float* b2 = (const float*)d_in[6];
  float* y = (float*)d_out;

  char* ws = (char*)d_ws;
  int*   counts = (int*)(ws + 0);
  int*   kept   = (int*)(ws + 64);
  float* imp    = (float*)(ws + 128);
  int*   padoff = (int*)(ws + 192);
  int*   list   = (int*)(ws + 4096);                           // 512 KiB
  float* wtok   = (float*)(ws + 4096 + 524288);                // 512 KiB
  int*   tki    = (int*)(ws + 4096 + 2*524288);                // 128 KiB
  float* tkw    = (float*)(ws + 4096 + 2*524288 + 131072);     // 128 KiB
  unsigned char* x8   = (unsigned char*)(ws + 0x180000);       // 16 MiB
  unsigned char* wt8  = (unsigned char*)(ws + 0x1180000);      // 32 MiB (shared w1t8/w2t8)
  unsigned char* hid8 = (unsigned char*)(ws + 0x3180000);      // 68 MiB
  // total 0x7580000 = 117.5 MiB

  hipMemsetAsync(ws, 0, 4096, stream);
  hipMemsetAsync(d_out, 0, (size_t)out_size * sizeof(float), stream);

  convx_kernel<<<NT*DIM/4/256, 256, 0, stream>>>(x, (unsigned*)x8);
  router_kernel<<<256, 256, 0, stream>>>(x, rw, rb, tki, tkw, counts, imp);
  build_lists_kernel<<<16, 1024, 0, stream>>>(tki, tkw, list, wtok, kept);
  finalize_kernel<<<1, 64, 0, stream>>>(counts, imp, kept, padoff, y + (size_t)NT*DIM);
  prepw_kernel<<<dim3(HID/64, DIM/64, NE), 256, 0, stream>>>(w1, wt8, DIM, HID, 16.f);
  gemm1_kernel<<<dim3(16, 64, 16), 256, 0, stream>>>(x8, wt8, b1, list, kept, padoff, hid8);
  prepw_kernel<<<dim3(DIM/64, HID/64, NE), 256, 0, stream>>>(w2, wt8, HID, DIM, 16.f);
  gemm2_kernel<<<dim3(8, 64, 16), 256, 0, stream>>>(hid8, wt8, b2, list, wtok, kept, padoff, y);
}

// Round 3
// 935.537 us; speedup vs baseline: 1.4692x; 1.0200x over previous
//
#include <hip/hip_runtime.h>
#include <math.h>

#define NT   16384
#define DIM  1024
#define HID  2048
#define NE   16
#define CAP  8192
#define BK   64

typedef __attribute__((ext_vector_type(4))) short short4v;
typedef __attribute__((ext_vector_type(4))) float f32x4;
typedef long long i64;
typedef __attribute__((ext_vector_type(2))) long long i64x2;

__device__ __forceinline__ short f2bf(float f){
  union { float f; unsigned u; } c; c.f = f;
  unsigned r = (c.u + 0x7fffu + ((c.u >> 16) & 1u)) >> 16;
  return (short)r;
}
__device__ __forceinline__ float bf2f(short s){
  union { unsigned u; float f; } c; c.u = ((unsigned)(unsigned short)s) << 16;
  return c.f;
}
__device__ __forceinline__ unsigned pk4fp8(float a, float b, float c, float d){
  int lo  = __builtin_amdgcn_cvt_pk_fp8_f32(a, b, 0, false);
  int all = __builtin_amdgcn_cvt_pk_fp8_f32(c, d, lo, true);
  return (unsigned)all;
}
__device__ __forceinline__ unsigned char fp8one(float a){
  return (unsigned char)(__builtin_amdgcn_cvt_pk_fp8_f32(a, a, 0, false) & 0xff);
}

#define GLOAD16(g, l) __builtin_amdgcn_global_load_lds( \
    (const __attribute__((address_space(1))) void*)(g), \
    (__attribute__((address_space(3))) void*)(l), 16, 0, 0)

// permuted dword index within a 64-byte K-chunk: source dword c4 (0..15) ->
// dest dword kq*4 + kk*2 + jdw  (kq=(c4>>1)&3, kk=c4>>3, jdw=c4&1)
__device__ __forceinline__ int permdw(int c4){
  return ((c4>>1)&3)*4 + (c4>>3)*2 + (c4&1);
}

// ---------------- x -> fp8 (row-permuted for MFMA fragment order) ----------
__global__ __launch_bounds__(256) void convx_kernel(const float* __restrict__ x,
                                                    unsigned* __restrict__ x8){
  int idx = blockIdx.x*256 + threadIdx.x;   // dword index, 256 dwords/row
  int row = idx >> 8, d = idx & 255;
  int chunk = d >> 4, c4 = d & 15;
  float4 v = ((const float4*)x)[idx];
  x8[row*256 + chunk*16 + permdw(c4)] = pk4fp8(v.x, v.y, v.z, v.w);
}

// ---------------- w [E][K][N] f32 -> wt8 [E][N][K] fp8 x16, permuted -------
__global__ __launch_bounds__(256) void prepw_kernel(const float* __restrict__ w,
                                                    unsigned char* __restrict__ wt8,
                                                    int K, int N, float scale){
  __shared__ float T[64][65];
  int e = blockIdx.z;
  int n0 = blockIdx.x*64, k0 = blockIdx.y*64;
  const float* we = w + (size_t)e*K*N;
  unsigned char* oe = wt8 + (size_t)e*K*N;
  int tid = threadIdx.x;
  int rr = tid >> 4, c4 = tid & 15;
#pragma unroll
  for (int p = 0; p < 4; ++p){
    int r = rr + p*16;
    float4 v = *(const float4*)(we + (size_t)(k0 + r)*N + n0 + c4*4);
    T[r][c4*4+0] = v.x*scale; T[r][c4*4+1] = v.y*scale;
    T[r][c4*4+2] = v.z*scale; T[r][c4*4+3] = v.w*scale;
  }
  __syncthreads();
  int dd = permdw(c4);
#pragma unroll
  for (int p = 0; p < 4; ++p){
    int n = rr + p*16;
    unsigned u = pk4fp8(T[c4*4+0][n], T[c4*4+1][n], T[c4*4+2][n], T[c4*4+3][n]);
    *(unsigned*)(oe + (size_t)(n0 + n)*K + k0 + dd*4) = u;
  }
}

// ---------------- router ----------------------------------------------------
__global__ __launch_bounds__(256) void router_kernel(
    const float* __restrict__ x, const float* __restrict__ rw, const float* __restrict__ rb,
    int* __restrict__ tki, float* __restrict__ tkw,
    int* __restrict__ counts, float* __restrict__ importance)
{
  __shared__ short WsB[1024*20];
  __shared__ float Rb[16];
  int tid = threadIdx.x;
  for (int i = tid; i < 1024*16; i += 256){
    int k = i >> 4, e2 = i & 15;
    WsB[k*20 + e2] = f2bf(rw[i]);
  }
  if (tid < 16) Rb[tid] = rb[tid];
  __syncthreads();
  int wave = tid >> 6, lane = tid & 63;
  float impAcc[16]; int cntAcc[16];
#pragma unroll
  for (int e=0;e<16;e++){ impAcc[e]=0.f; cntAcc[e]=0; }
  for (int t = 0; t < 16; ++t){
    int tok = blockIdx.x*64 + wave*16 + t;
    const float* xr = x + (size_t)tok*DIM;
    float p[16];
#pragma unroll
    for (int e=0;e<16;e++) p[e]=0.f;
    for (int j = 0; j < 16; ++j){
      int k = lane + 64*j;
      float xv = xr[k];
      const short* wr0 = &WsB[k*20];
#pragma unroll
      for (int q=0;q<4;q++){
        short4v w4 = *(const short4v*)(wr0 + q*4);
        p[4*q+0] += xv * bf2f(w4[0]);
        p[4*q+1] += xv * bf2f(w4[1]);
        p[4*q+2] += xv * bf2f(w4[2]);
        p[4*q+3] += xv * bf2f(w4[3]);
      }
    }
#pragma unroll
    for (int e=0;e<16;e++){
      float v = p[e];
#pragma unroll
      for (int off=32; off>0; off>>=1) v += __shfl_xor(v, off, 64);
      p[e] = v + Rb[e];
    }
    float mx = p[0];
#pragma unroll
    for (int e=1;e<16;e++) mx = fmaxf(mx, p[e]);
    float s = 0.f;
#pragma unroll
    for (int e=0;e<16;e++){ p[e] = expf(p[e]-mx); s += p[e]; }
    float inv = 1.f/s;
#pragma unroll
    for (int e=0;e<16;e++) p[e] *= inv;
    float v1=-1.f, v2=-1.f; int i1=0, i2=0;
#pragma unroll
    for (int e=0;e<16;e++){
      float pe = p[e];
      if (pe > v1){ v2=v1; i2=i1; v1=pe; i1=e; }
      else if (pe > v2){ v2=pe; i2=e; }
    }
    if (lane==0){
      tki[2*tok] = i1; tki[2*tok+1] = i2;
      tkw[2*tok] = v1; tkw[2*tok+1] = v2;
    }
#pragma unroll
    for (int e=0;e<16;e++){
      impAcc[e] += p[e];
      cntAcc[e] += (i1==e) + (i2==e);
    }
  }
  if (lane==0){
#pragma unroll
    for (int e=0;e<16;e++){
      atomicAdd(&importance[e], impAcc[e]);
      atomicAdd(&counts[e], cntAcc[e]);
    }
  }
}

// ---------------- per-expert ordered token lists ----------------------------
__global__ __launch_bounds__(1024) void build_lists_kernel(
    const int* __restrict__ tki, const float* __restrict__ tkw,
    int* __restrict__ list, float* __restrict__ wtok, int* __restrict__ keptArr)
{
  __shared__ int sc[1024];
  int e = blockIdx.x;
  int tid = threadIdx.x;
  int base = 0;
  for (int c = 0; c < NT/1024; ++c){
    int t = c*1024 + tid;
    int i1 = tki[2*t], i2 = tki[2*t+1];
    int mask = (i1==e || i2==e) ? 1 : 0;
    sc[tid] = mask;
    __syncthreads();
    for (int off=1; off<1024; off<<=1){
      int v = (tid>=off) ? sc[tid-off] : 0;
      __syncthreads();
      sc[tid] += v;
      __syncthreads();
    }
    int rank = base + sc[tid] - mask;
    if (mask && rank < CAP){
      list[e*CAP + rank] = t;
      wtok[e*CAP + rank] = (i1==e) ? tkw[2*t] : tkw[2*t+1];
    }
    base += sc[1023];
    __syncthreads();
  }
  if (tid==0) keptArr[e] = min(base, CAP);
}

// ---------------- aux loss + padded (256) row offsets -----------------------
__global__ void finalize_kernel(const int* __restrict__ counts, const float* __restrict__ importance,
                                const int* __restrict__ keptArr, int* __restrict__ padOff,
                                float* __restrict__ auxOut)
{
  if (threadIdx.x == 0 && blockIdx.x == 0){
    float bal = 0.f, il = 0.f;
    int po = 0;
    padOff[0] = 0;
    for (int e=0;e<16;e++){
      float im = importance[e];
      float cf = (float)counts[e];
      bal += (im * (1.f/NT)) * (cf * (1.f/NT));
      il  += im*im;
      po  += ((keptArr[e] + 255) >> 8) << 8;
      padOff[e+1] = po;
    }
    auxOut[0] = bal * 16.f + il * (1.f/16.f);
  }
}

// ======================= pipelined 256x256 fp8 GEMM core ====================
// 3-buffer LDS (32KB each: A 16KB + B 16KB), counted vmcnt, 8 waves (2x4).

#define MFMA8(af, bf, ACCROW) \
  _Pragma("unroll") \
  for (int j=0;j<4;j++){ \
    ACCROW[j] = __builtin_amdgcn_mfma_f32_16x16x32_fp8_fp8(af[0], bf[j][0], ACCROW[j], 0,0,0); \
    ACCROW[j] = __builtin_amdgcn_mfma_f32_16x16x32_fp8_fp8(af[1], bf[j][1], ACCROW[j], 0,0,0); \
  }

// ---------------- GEMM1: hid8 = gelu(gather(x8) @ w1t8^T /16 + b1) ----------
__global__ __launch_bounds__(512, 2) void gemm1_kernel(
    const unsigned char* __restrict__ x8, const unsigned char* __restrict__ w1t8,
    const float* __restrict__ b1, const int* __restrict__ list,
    const int* __restrict__ keptArr, const int* __restrict__ padOff,
    unsigned char* __restrict__ hid8)
{
  __shared__ unsigned char lds[98304];
  int e = blockIdx.z;
  int kept = keptArr[e];
  int mt = blockIdx.y;
  if (mt*256 >= kept) return;
  int n0 = blockIdx.x * 256;

  const unsigned char* Wg = w1t8 + (size_t)e*DIM*HID;
  const int* lst = list + e*CAP;
  int tid = threadIdx.x;
  int lane = tid & 63, wv = tid >> 6;
  int wr = wv >> 2, wc = wv & 3;
  int l15 = lane & 15, kq = lane >> 4;

  int srow = tid >> 2, g = tid & 3;
  const unsigned char* pA[2]; const unsigned char* pB[2];
#pragma unroll
  for (int li=0; li<2; ++li){
    int row = li*128 + srow;
    int gm = mt*256 + row;
    int tok = lst[min(gm, kept-1)];
    pA[li] = x8 + (size_t)tok*DIM + ((g ^ (row&3))<<4);
    pB[li] = Wg + (size_t)(n0 + row)*DIM + ((g ^ (row&3))<<4);
  }

  int swz = (kq ^ (l15&3)) << 4;
  int offA0 = (wr*128 + l15)*64 + swz;
  int offB0 = 16384 + (wc*64 + l15)*64 + swz;

  f32x4 acc[8][4];
#pragma unroll
  for (int i=0;i<8;i++)
#pragma unroll
    for (int j=0;j<4;j++) acc[i][j] = (f32x4){0.f,0.f,0.f,0.f};

  // prologue: stage tiles 0,1
#pragma unroll
  for (int pt=0; pt<2; ++pt){
    unsigned char* db = lds + pt*32768;
    GLOAD16(pA[0], db + tid*16);         GLOAD16(pA[1], db + 8192 + tid*16);
    GLOAD16(pB[0], db + 16384 + tid*16); GLOAD16(pB[1], db + 24576 + tid*16);
    pA[0]+=BK; pA[1]+=BK; pB[0]+=BK; pB[1]+=BK;
  }
  asm volatile("s_waitcnt vmcnt(4)" ::: "memory");
  __builtin_amdgcn_s_barrier();

  int cur = 0, sbuf = 2;
  const int nt = DIM/BK;   // 16
  for (int t = 0; t < nt; ++t){
    const unsigned char* bt = lds + cur*32768;
    unsigned char* db = lds + sbuf*32768;
    bool st = (t+2 < nt);
    if (st){ GLOAD16(pA[0], db + tid*16); GLOAD16(pA[1], db + 8192 + tid*16); }
    i64x2 bf[4], af[4];
#pragma unroll
    for (int j=0;j<4;j++) bf[j] = *(const i64x2*)(bt + offB0 + j*1024);
#pragma unroll
    for (int i=0;i<4;i++) af[i] = *(const i64x2*)(bt + offA0 + i*1024);
    __builtin_amdgcn_s_setprio(1);
#pragma unroll
    for (int i=0;i<4;i++){ MFMA8(af[i], bf, acc[i]); }
    __builtin_amdgcn_s_setprio(0);
    if (st){
      GLOAD16(pB[0], db + 16384 + tid*16); GLOAD16(pB[1], db + 24576 + tid*16);
      pA[0]+=BK; pA[1]+=BK; pB[0]+=BK; pB[1]+=BK;
      sbuf = sbuf==2 ? 0 : sbuf+1;
    }
#pragma unroll
    for (int i=0;i<4;i++) af[i] = *(const i64x2*)(bt + offA0 + (i+4)*1024);
    __builtin_amdgcn_s_setprio(1);
#pragma unroll
    for (int i=0;i<4;i++){ MFMA8(af[i], bf, acc[i+4]); }
    __builtin_amdgcn_s_setprio(0);
    if (t+1 < nt){
      if (t+2 < nt) asm volatile("s_waitcnt vmcnt(4)" ::: "memory");
      else          asm volatile("s_waitcnt vmcnt(0)" ::: "memory");
      __builtin_amdgcn_s_barrier();
      cur = cur==2 ? 0 : cur+1;
    }
  }

  // epilogue: bias + gelu -> fp8, repack via LDS, coalesced 16B stores
  __builtin_amdgcn_s_barrier();
  const float* b1e = b1 + (size_t)e*HID;
  int rg = lane >> 4, cl = l15;
#pragma unroll
  for (int i=0;i<8;i++){
#pragma unroll
    for (int j=0;j<4;j++){
      int c = wc*64 + j*16 + cl;
      float bias = b1e[n0 + c];
      int cc = c & 63, chunk = c >> 6;
      int pc = chunk*64 + ((cc>>3)&3)*16 + (cc>>5)*8 + (cc&7);
#pragma unroll
      for (int r=0;r<4;r++){
        int lrow = wr*128 + i*16 + rg*4 + r;
        float v = acc[i][j][r]*(1.f/16.f) + bias;
        float s = 1.f/(1.f + __expf(-1.702f*v));   // sigmoid-approx GELU
        lds[lrow*256 + (pc ^ ((lrow&15)<<4))] = fp8one(v*s);
      }
    }
  }
  __builtin_amdgcn_s_barrier();
  size_t rowBase = (size_t)padOff[e] + (size_t)mt*256;
#pragma unroll
  for (int w=0; w<8; ++w){
    int idx = w*512 + tid;
    int row = idx >> 4, co = (idx & 15)*16;
    *(i64x2*)(hid8 + (rowBase + row)*HID + n0 + co) =
        *(const i64x2*)(lds + row*256 + (co ^ ((row&15)<<4)));
  }
}

// ---------------- GEMM2: y[tok] += (hid8 @ w2t8^T /16 + b2) * w_tok ---------
__global__ __launch_bounds__(512, 2) void gemm2_kernel(
    const unsigned char* __restrict__ hid8, const unsigned char* __restrict__ w2t8,
    const float* __restrict__ b2, const int* __restrict__ list,
    const float* __restrict__ wtok, const int* __restrict__ keptArr,
    const int* __restrict__ padOff, float* __restrict__ y)
{
  __shared__ unsigned char lds[98304];
  int e = blockIdx.z;
  int kept = keptArr[e];
  int mt = blockIdx.y;
  if (mt*256 >= kept) return;
  int n0 = blockIdx.x * 256;

  const unsigned char* Wg = w2t8 + (size_t)e*HID*DIM;
  const unsigned char* hb = hid8 + ((size_t)padOff[e] + (size_t)mt*256)*HID;
  int tid = threadIdx.x;
  int lane = tid & 63, wv = tid >> 6;
  int wr = wv >> 2, wc = wv & 3;
  int l15 = lane & 15, kq = lane >> 4;

  int srow = tid >> 2, g = tid & 3;
  const unsigned char* pA[2]; const unsigned char* pB[2];
#pragma unroll
  for (int li=0; li<2; ++li){
    int row = li*128 + srow;
    pA[li] = hb + (size_t)row*HID + ((g ^ (row&3))<<4);
    pB[li] = Wg + (size_t)(n0 + row)*HID + ((g ^ (row&3))<<4);
  }

  int swz = (kq ^ (l15&3)) << 4;
  int offA0 = (wr*128 + l15)*64 + swz;
  int offB0 = 16384 + (wc*64 + l15)*64 + swz;

  f32x4 acc[8][4];
#pragma unroll
  for (int i=0;i<8;i++)
#pragma unroll
    for (int j=0;j<4;j++) acc[i][j] = (f32x4){0.f,0.f,0.f,0.f};

#pragma unroll
  for (int pt=0; pt<2; ++pt){
    unsigned char* db = lds + pt*32768;
    GLOAD16(pA[0], db + tid*16);         GLOAD16(pA[1], db + 8192 + tid*16);
    GLOAD16(pB[0], db + 16384 + tid*16); GLOAD16(pB[1], db + 24576 + tid*16);
    pA[0]+=BK; pA[1]+=BK; pB[0]+=BK; pB[1]+=BK;
  }
  asm volatile("s_waitcnt vmcnt(4)" ::: "memory");
  __builtin_amdgcn_s_barrier();

  int cur = 0, sbuf = 2;
  const int nt = HID/BK;   // 32
  for (int t = 0; t < nt; ++t){
    const unsigned char* bt = lds + cur*32768;
    unsigned char* db = lds + sbuf*32768;
    bool st = (t+2 < nt);
    if (st){ GLOAD16(pA[0], db + tid*16); GLOAD16(pA[1], db + 8192 + tid*16); }
    i64x2 bf[4], af[4];
#pragma unroll
    for (int j=0;j<4;j++) bf[j] = *(const i64x2*)(bt + offB0 + j*1024);
#pragma unroll
    for (int i=0;i<4;i++) af[i] = *(const i64x2*)(bt + offA0 + i*1024);
    __builtin_amdgcn_s_setprio(1);
#pragma unroll
    for (int i=0;i<4;i++){ MFMA8(af[i], bf, acc[i]); }
    __builtin_amdgcn_s_setprio(0);
    if (st){
      GLOAD16(pB[0], db + 16384 + tid*16); GLOAD16(pB[1], db + 24576 + tid*16);
      pA[0]+=BK; pA[1]+=BK; pB[0]+=BK; pB[1]+=BK;
      sbuf = sbuf==2 ? 0 : sbuf+1;
    }
#pragma unroll
    for (int i=0;i<4;i++) af[i] = *(const i64x2*)(bt + offA0 + (i+4)*1024);
    __builtin_amdgcn_s_setprio(1);
#pragma unroll
    for (int i=0;i<4;i++){ MFMA8(af[i], bf, acc[i+4]); }
    __builtin_amdgcn_s_setprio(0);
    if (t+1 < nt){
      if (t+2 < nt) asm volatile("s_waitcnt vmcnt(4)" ::: "memory");
      else          asm volatile("s_waitcnt vmcnt(0)" ::: "memory");
      __builtin_amdgcn_s_barrier();
      cur = cur==2 ? 0 : cur+1;
    }
  }

  const float* b2e = b2 + (size_t)e*DIM;
  const int*   lst = list + e*CAP;
  const float* wt  = wtok + e*CAP;
  int rg = lane >> 4, cl = l15;
#pragma unroll
  for (int i=0;i<8;i++){
#pragma unroll
    for (int r=0;r<4;r++){
      int m = mt*256 + wr*128 + i*16 + rg*4 + r;
      if (m < kept){
        int tok = lst[m];
        float w = wt[m];
#pragma unroll
        for (int j=0;j<4;j++){
          int n = n0 + wc*64 + j*16 + cl;
          float v = acc[i][j][r]*(1.f/16.f) + b2e[n];
          atomicAdd(y + (size_t)tok*DIM + n, v*w);
        }
      }
    }
  }
}

// ---------------- launch ----------------------------------------------------
extern "C" void kernel_launch(void* const* d_in, const int* in_sizes, int n_in,
                              void* d_out, int out_size, void* d_ws, size_t ws_size,
                              hipStream_t stream)
{
  (void)in_sizes; (void)n_in; (void)ws_size;
  const float* x  = (const float*)d_in[0];
  const float* rw = (const float*)d_in[1];
  const float* rb = (const float*)d_in[2];
  const float* w1 = (const float*)d_in[3];
  const float* b1 = (const float*)d_in[4];
  const float* w2 = (const float*)d_in[5];
  const float* b2 = (const float*)d_in[6];
  float* y = (float*)d_out;

  char* ws = (char*)d_ws;
  int*   counts = (int*)(ws + 0);
  int*   kept   = (int*)(ws + 64);
  float* imp    = (float*)(ws + 128);
  int*   padoff = (int*)(ws + 192);
  int*   list   = (int*)(ws + 4096);                           // 512 KiB
  float* wtok   = (float*)(ws + 4096 + 524288);                // 512 KiB
  int*   tki    = (int*)(ws + 4096 + 2*524288);                // 128 KiB
  float* tkw    = (float*)(ws + 4096 + 2*524288 + 131072);     // 128 KiB
  unsigned char* x8   = (unsigned char*)(ws + 0x180000);       // 16 MiB
  unsigned char* wt8  = (unsigned char*)(ws + 0x1180000);      // 32 MiB (shared)
  unsigned char* hid8 = (unsigned char*)(ws + 0x3180000);      // ~72 MiB
  // total ~127.4 MiB

  hipMemsetAsync(ws, 0, 4096, stream);
  hipMemsetAsync(d_out, 0, (size_t)out_size * sizeof(float), stream);

  convx_kernel<<<NT*DIM/4/256, 256, 0, stream>>>(x, (unsigned*)x8);
  router_kernel<<<256, 256, 0, stream>>>(x, rw, rb, tki, tkw, counts, imp);
  build_lists_kernel<<<16, 1024, 0, stream>>>(tki, tkw, list, wtok, kept);
  finalize_kernel<<<1, 64, 0, stream>>>(counts, imp, kept, padoff, y + (size_t)NT*DIM);
  prepw_kernel<<<dim3(HID/64, DIM/64, NE), 256, 0, stream>>>(w1, wt8, DIM, HID, 16.f);
  gemm1_kernel<<<dim3(HID/256, CAP/256, NE), 512, 0, stream>>>(x8, wt8, b1, list, kept, padoff, hid8);
  prepw_kernel<<<dim3(DIM/64, HID/64, NE), 256, 0, stream>>>(w2, wt8, HID, DIM, 16.f);
  gemm2_kernel<<<dim3(DIM/256, CAP/256, NE), 512, 0, stream>>>(hid8, wt8, b2, list, wtok, kept, padoff, y);
}

// Round 4
// 687.035 us; speedup vs baseline: 2.0006x; 1.3617x over previous
//
#include <hip/hip_runtime.h>
#include <math.h>

#define NT   16384
#define DIM  1024
#define HID  2048
#define NE   16
#define CAP  8192
#define BK   64

typedef __attribute__((ext_vector_type(4))) short short4v;
typedef __attribute__((ext_vector_type(4))) float f32x4;
typedef long long i64;
typedef __attribute__((ext_vector_type(2))) long long i64x2;

__device__ __forceinline__ short f2bf(float f){
  union { float f; unsigned u; } c; c.f = f;
  unsigned r = (c.u + 0x7fffu + ((c.u >> 16) & 1u)) >> 16;
  return (short)r;
}
__device__ __forceinline__ float bf2f(short s){
  union { unsigned u; float f; } c; c.u = ((unsigned)(unsigned short)s) << 16;
  return c.f;
}
__device__ __forceinline__ unsigned pk4fp8(float a, float b, float c, float d){
  int lo  = __builtin_amdgcn_cvt_pk_fp8_f32(a, b, 0, false);
  int all = __builtin_amdgcn_cvt_pk_fp8_f32(c, d, lo, true);
  return (unsigned)all;
}
__device__ __forceinline__ unsigned char fp8one(float a){
  return (unsigned char)(__builtin_amdgcn_cvt_pk_fp8_f32(a, a, 0, false) & 0xff);
}
// OCP e4m3fn decode (no builtin dependency)
__device__ __forceinline__ float fp8dec(unsigned b){
  unsigned e = (b >> 3) & 15u, m = b & 7u;
  union { unsigned u; float f; } c;
  if (e) { c.u = ((b & 0x80u) << 24) | ((e + 120u) << 23) | (m << 20); return c.f; }
  float mag = (float)m * 0.001953125f;
  return (b & 0x80u) ? -mag : mag;
}

#define GLOAD16(g, l) __builtin_amdgcn_global_load_lds( \
    (const __attribute__((address_space(1))) void*)(g), \
    (__attribute__((address_space(3))) void*)(l), 16, 0, 0)

// dword permutation within a 64B k-chunk so lane kq's two i64 MFMA frags are
// one contiguous b128 at unit kq:  d -> kq(d)*4 + kk(d)*2 + pair(d)
__device__ __forceinline__ int permdw(int c4){
  return ((c4>>1)&3)*4 + (c4>>3)*2 + (c4&1);
}

// ---------------- x -> fp8 (permuted) ---------------------------------------
__global__ __launch_bounds__(256) void convx_kernel(const float* __restrict__ x,
                                                    unsigned* __restrict__ x8){
  int idx = blockIdx.x*256 + threadIdx.x;
  int row = idx >> 8, d = idx & 255;
  int chunk = d >> 4, c4 = d & 15;
  float4 v = ((const float4*)x)[idx];
  x8[row*256 + chunk*16 + permdw(c4)] = pk4fp8(v.x, v.y, v.z, v.w);
}

// ---------------- w [E][K][N] f32 -> wt8 [E][N][K] fp8 x16, permuted --------
__global__ __launch_bounds__(256) void prepw_kernel(const float* __restrict__ w,
                                                    unsigned char* __restrict__ wt8,
                                                    int K, int N, float scale){
  __shared__ float T[64][65];
  int e = blockIdx.z;
  int n0 = blockIdx.x*64, k0 = blockIdx.y*64;
  const float* we = w + (size_t)e*K*N;
  unsigned char* oe = wt8 + (size_t)e*K*N;
  int tid = threadIdx.x;
  int rr = tid >> 4, c4 = tid & 15;
#pragma unroll
  for (int p = 0; p < 4; ++p){
    int r = rr + p*16;
    float4 v = *(const float4*)(we + (size_t)(k0 + r)*N + n0 + c4*4);
    T[r][c4*4+0] = v.x*scale; T[r][c4*4+1] = v.y*scale;
    T[r][c4*4+2] = v.z*scale; T[r][c4*4+3] = v.w*scale;
  }
  __syncthreads();
  int dd = permdw(c4);
#pragma unroll
  for (int p = 0; p < 4; ++p){
    int n = rr + p*16;
    unsigned u = pk4fp8(T[c4*4+0][n], T[c4*4+1][n], T[c4*4+2][n], T[c4*4+3][n]);
    *(unsigned*)(oe + (size_t)(n0 + n)*K + k0 + dd*4) = u;
  }
}

// ---------------- router ----------------------------------------------------
__global__ __launch_bounds__(256) void router_kernel(
    const float* __restrict__ x, const float* __restrict__ rw, const float* __restrict__ rb,
    int* __restrict__ tki, float* __restrict__ tkw,
    int* __restrict__ counts, float* __restrict__ importance)
{
  __shared__ short WsB[1024*20];
  __shared__ float Rb[16];
  int tid = threadIdx.x;
  for (int i = tid; i < 1024*16; i += 256){
    int k = i >> 4, e2 = i & 15;
    WsB[k*20 + e2] = f2bf(rw[i]);
  }
  if (tid < 16) Rb[tid] = rb[tid];
  __syncthreads();
  int wave = tid >> 6, lane = tid & 63;
  float impAcc[16]; int cntAcc[16];
#pragma unroll
  for (int e=0;e<16;e++){ impAcc[e]=0.f; cntAcc[e]=0; }
  for (int t = 0; t < 16; ++t){
    int tok = blockIdx.x*64 + wave*16 + t;
    const float* xr = x + (size_t)tok*DIM;
    float p[16];
#pragma unroll
    for (int e=0;e<16;e++) p[e]=0.f;
    for (int j = 0; j < 16; ++j){
      int k = lane + 64*j;
      float xv = xr[k];
      const short* wr0 = &WsB[k*20];
#pragma unroll
      for (int q=0;q<4;q++){
        short4v w4 = *(const short4v*)(wr0 + q*4);
        p[4*q+0] += xv * bf2f(w4[0]);
        p[4*q+1] += xv * bf2f(w4[1]);
        p[4*q+2] += xv * bf2f(w4[2]);
        p[4*q+3] += xv * bf2f(w4[3]);
      }
    }
#pragma unroll
    for (int e=0;e<16;e++){
      float v = p[e];
#pragma unroll
      for (int off=32; off>0; off>>=1) v += __shfl_xor(v, off, 64);
      p[e] = v + Rb[e];
    }
    float mx = p[0];
#pragma unroll
    for (int e=1;e<16;e++) mx = fmaxf(mx, p[e]);
    float s = 0.f;
#pragma unroll
    for (int e=0;e<16;e++){ p[e] = expf(p[e]-mx); s += p[e]; }
    float inv = 1.f/s;
#pragma unroll
    for (int e=0;e<16;e++) p[e] *= inv;
    float v1=-1.f, v2=-1.f; int i1=0, i2=0;
#pragma unroll
    for (int e=0;e<16;e++){
      float pe = p[e];
      if (pe > v1){ v2=v1; i2=i1; v1=pe; i1=e; }
      else if (pe > v2){ v2=pe; i2=e; }
    }
    if (lane==0){
      tki[2*tok] = i1; tki[2*tok+1] = i2;
      tkw[2*tok] = v1; tkw[2*tok+1] = v2;
    }
#pragma unroll
    for (int e=0;e<16;e++){
      impAcc[e] += p[e];
      cntAcc[e] += (i1==e) + (i2==e);
    }
  }
  if (lane==0){
#pragma unroll
    for (int e=0;e<16;e++){
      atomicAdd(&importance[e], impAcc[e]);
      atomicAdd(&counts[e], cntAcc[e]);
    }
  }
}

// ---------------- per-expert ordered lists (ballot scan) --------------------
// wtok sign encodes top-k position: +w for k=0 (top-1), -w for k=1 (top-2)
__global__ __launch_bounds__(1024) void build_lists_kernel(
    const int* __restrict__ tki, const float* __restrict__ tkw,
    int* __restrict__ list, float* __restrict__ wtok, int* __restrict__ keptArr)
{
  __shared__ int swsum[16];
  int e = blockIdx.x;
  int tid = threadIdx.x, wid = tid >> 6, lane = tid & 63;
  int base = 0;
  for (int c = 0; c < NT/1024; ++c){
    int t = c*1024 + tid;
    int i1 = tki[2*t], i2 = tki[2*t+1];
    bool m = (i1==e) || (i2==e);
    unsigned long long bal = __ballot(m);
    int inw = __popcll(bal & ((1ull << lane) - 1ull));
    if (lane == 0) swsum[wid] = __popcll(bal);
    __syncthreads();
    int pre = 0, tot = 0;
#pragma unroll
    for (int w = 0; w < 16; ++w){
      int v = swsum[w];
      tot += v;
      if (w < wid) pre += v;
    }
    int rank = base + pre + inw;
    if (m && rank < CAP){
      list[e*CAP + rank] = t;
      wtok[e*CAP + rank] = (i1==e) ? tkw[2*t] : -tkw[2*t+1];
    }
    base += tot;
    __syncthreads();
  }
  if (tid==0) keptArr[e] = min(base, CAP);
}

// ---------------- aux loss + padded (128) row offsets -----------------------
__global__ void finalize_kernel(const int* __restrict__ counts, const float* __restrict__ importance,
                                const int* __restrict__ keptArr, int* __restrict__ padOff,
                                float* __restrict__ auxOut)
{
  if (threadIdx.x == 0 && blockIdx.x == 0){
    float bal = 0.f, il = 0.f;
    int po = 0;
    padOff[0] = 0;
    for (int e=0;e<16;e++){
      float im = importance[e];
      float cf = (float)counts[e];
      bal += (im * (1.f/NT)) * (cf * (1.f/NT));
      il  += im*im;
      po  += ((keptArr[e] + 127) >> 7) << 7;
      padOff[e+1] = po;
    }
    auxOut[0] = bal * 16.f + il * (1.f/16.f);
  }
}

// ======== 128x128 fp8 GEMM, 4 waves, dbuf LDS, stage-early 2-phase ==========

#define STAGE(b) do{ \
  GLOAD16(pA0, lds + (b)*8192 + tid*16); \
  GLOAD16(pA1, lds + (b)*8192 + 4096 + tid*16); \
  GLOAD16(pB0, lds + 16384 + (b)*8192 + tid*16); \
  GLOAD16(pB1, lds + 16384 + (b)*8192 + 4096 + tid*16); \
  pA0 += BK; pA1 += BK; pB0 += BK; pB1 += BK; }while(0)

#define GEMM_FRAGS_AND_MFMA(At, Bt) \
  i64x2 bf[4], af[4]; \
  _Pragma("unroll") for (int j=0;j<4;j++) \
    bf[j] = *(const i64x2*)((Bt) + ((wc*64 + j*16 + l15)<<6) + rdsw); \
  _Pragma("unroll") for (int i=0;i<4;i++) \
    af[i] = *(const i64x2*)((At) + ((wr*64 + i*16 + l15)<<6) + rdsw);

// ---------------- GEMM1: hid8 = gelu(gather(x8) @ w1t8^T /16 + b1) ----------
__global__ __launch_bounds__(256, 3) void gemm1_kernel(
    const unsigned char* __restrict__ x8, const unsigned char* __restrict__ w1t8,
    const float* __restrict__ b1, const int* __restrict__ list,
    const int* __restrict__ keptArr, const int* __restrict__ padOff,
    unsigned char* __restrict__ hid8)
{
  __shared__ unsigned char lds[32768];  // A 2x8K @0, B 2x8K @16K; epilogue reuse
  int e = blockIdx.z;
  int kept = keptArr[e];
  int mt = blockIdx.y;
  if (mt*128 >= kept) return;
  int n0 = blockIdx.x * 128;

  const unsigned char* Wg = w1t8 + (size_t)e*DIM*HID;
  const int* lst = list + e*CAP;
  int tid = threadIdx.x;
  int lane = tid & 63, wv = tid >> 6;
  int wr = wv >> 1, wc = wv & 1;
  int l15 = lane & 15, kq = lane >> 4;
  int s2r = (l15 >> 1) & 3;
  int rdsw = (kq ^ s2r) << 4;

  int srow = tid >> 2, su = tid & 3;
  int r0 = srow, r1 = 64 + srow;
  int sx0 = (su ^ ((r0>>1)&3)) << 4, sx1 = (su ^ ((r1>>1)&3)) << 4;
  int t0 = lst[min(mt*128 + r0, kept-1)];
  int t1 = lst[min(mt*128 + r1, kept-1)];
  const unsigned char* pA0 = x8 + (size_t)t0*DIM + sx0;
  const unsigned char* pA1 = x8 + (size_t)t1*DIM + sx1;
  const unsigned char* pB0 = Wg + (size_t)(n0 + r0)*DIM + sx0;
  const unsigned char* pB1 = Wg + (size_t)(n0 + r1)*DIM + sx1;

  f32x4 acc[4][4];
#pragma unroll
  for (int i=0;i<4;i++)
#pragma unroll
    for (int j=0;j<4;j++) acc[i][j] = (f32x4){0.f,0.f,0.f,0.f};

  STAGE(0);
  asm volatile("s_waitcnt vmcnt(0)" ::: "memory");
  __builtin_amdgcn_s_barrier();

  const int nt = DIM/BK;   // 16
  for (int t = 0; t < nt; ++t){
    const unsigned char* At = lds + (t&1)*8192;
    const unsigned char* Bt = lds + 16384 + (t&1)*8192;
    GEMM_FRAGS_AND_MFMA(At, Bt)
    if (t+1 < nt) STAGE((t+1)&1);
#pragma unroll
    for (int i=0;i<4;i++)
#pragma unroll
      for (int j=0;j<4;j++){
        acc[i][j] = __builtin_amdgcn_mfma_f32_16x16x32_fp8_fp8(af[i][0], bf[j][0], acc[i][j], 0,0,0);
        acc[i][j] = __builtin_amdgcn_mfma_f32_16x16x32_fp8_fp8(af[i][1], bf[j][1], acc[i][j], 0,0,0);
      }
    if (t+1 < nt){
      asm volatile("s_waitcnt vmcnt(0)" ::: "memory");
      __builtin_amdgcn_s_barrier();
    }
  }

  // epilogue: bias+gelu -> fp8 (permuted cols), LDS repack, 16B stores
  __builtin_amdgcn_s_barrier();
  const float* b1e = b1 + (size_t)e*HID;
  int rg = kq, cl = l15;
#pragma unroll
  for (int i=0;i<4;i++){
#pragma unroll
    for (int j=0;j<4;j++){
      int c = wc*64 + j*16 + cl;
      float bias = b1e[n0 + c];
      int cc = c & 63, ch = c >> 6;
      int tb = ch*64 + ((cc>>3)&3)*16 + (cc>>5)*8 + (cc&7);
#pragma unroll
      for (int r=0;r<4;r++){
        int lrow = wr*64 + i*16 + rg*4 + r;
        float v = acc[i][j][r]*(1.f/16.f) + bias;
        float s = 1.f/(1.f + __expf(-1.702f*v));
        lds[lrow*128 + (tb ^ ((lrow&7)<<4))] = fp8one(v*s);
      }
    }
  }
  __builtin_amdgcn_s_barrier();
  size_t rowBase = (size_t)padOff[e] + (size_t)mt*128;
#pragma unroll
  for (int w=0; w<4; ++w){
    int idx = w*256 + tid;
    int row = idx >> 3, u = idx & 7;
    *(i64x2*)(hid8 + (rowBase + row)*HID + n0 + u*16) =
        *(const i64x2*)(lds + row*128 + ((u*16) ^ ((row&7)<<4)));
  }
}

// ---------------- GEMM2: outb[k][tok] = fp8( w * (hid8 @ w2t8^T /16 + b2) ) -
__global__ __launch_bounds__(256, 3) void gemm2_kernel(
    const unsigned char* __restrict__ hid8, const unsigned char* __restrict__ w2t8,
    const float* __restrict__ b2, const int* __restrict__ list,
    const float* __restrict__ wtok, const int* __restrict__ keptArr,
    const int* __restrict__ padOff, unsigned char* __restrict__ outb)
{
  __shared__ unsigned char lds[32768];
  __shared__ int   s_tk[128];
  __shared__ float s_wv[128];
  int e = blockIdx.z;
  int kept = keptArr[e];
  int mt = blockIdx.y;
  if (mt*128 >= kept) return;
  int n0 = blockIdx.x * 128;

  const unsigned char* Wg = w2t8 + (size_t)e*HID*DIM;
  const unsigned char* hb = hid8 + ((size_t)padOff[e] + (size_t)mt*128)*HID;
  const int*   lst = list + e*CAP;
  const float* wt  = wtok + e*CAP;
  int tid = threadIdx.x;
  int lane = tid & 63, wv = tid >> 6;
  int wr = wv >> 1, wc = wv & 1;
  int l15 = lane & 15, kq = lane >> 4;
  int s2r = (l15 >> 1) & 3;
  int rdsw = (kq ^ s2r) << 4;

  if (tid < 128){
    int m = mt*128 + tid;
    if (m < kept){
      float we = wt[m];
      s_tk[tid] = lst[m] | ((we < 0.f) ? (1<<30) : 0);
      s_wv[tid] = fabsf(we);
    } else { s_tk[tid] = -1; s_wv[tid] = 0.f; }
  }

  int srow = tid >> 2, su = tid & 3;
  int r0 = srow, r1 = 64 + srow;
  int sx0 = (su ^ ((r0>>1)&3)) << 4, sx1 = (su ^ ((r1>>1)&3)) << 4;
  const unsigned char* pA0 = hb + (size_t)r0*HID + sx0;
  const unsigned char* pA1 = hb + (size_t)r1*HID + sx1;
  const unsigned char* pB0 = Wg + (size_t)(n0 + r0)*HID + sx0;
  const unsigned char* pB1 = Wg + (size_t)(n0 + r1)*HID + sx1;

  f32x4 acc[4][4];
#pragma unroll
  for (int i=0;i<4;i++)
#pragma unroll
    for (int j=0;j<4;j++) acc[i][j] = (f32x4){0.f,0.f,0.f,0.f};

  STAGE(0);
  asm volatile("s_waitcnt vmcnt(0)" ::: "memory");
  __builtin_amdgcn_s_barrier();

  const int nt = HID/BK;   // 32
  for (int t = 0; t < nt; ++t){
    const unsigned char* At = lds + (t&1)*8192;
    const unsigned char* Bt = lds + 16384 + (t&1)*8192;
    GEMM_FRAGS_AND_MFMA(At, Bt)
    if (t+1 < nt) STAGE((t+1)&1);
#pragma unroll
    for (int i=0;i<4;i++)
#pragma unroll
      for (int j=0;j<4;j++){
        acc[i][j] = __builtin_amdgcn_mfma_f32_16x16x32_fp8_fp8(af[i][0], bf[j][0], acc[i][j], 0,0,0);
        acc[i][j] = __builtin_amdgcn_mfma_f32_16x16x32_fp8_fp8(af[i][1], bf[j][1], acc[i][j], 0,0,0);
      }
    if (t+1 < nt){
      asm volatile("s_waitcnt vmcnt(0)" ::: "memory");
      __builtin_amdgcn_s_barrier();
    }
  }

  // epilogue: w*(acc/16 + b2) -> fp8, repack via LDS, 16B stores to outb
  __builtin_amdgcn_s_barrier();
  const float* b2e = b2 + (size_t)e*DIM;
  int rg = kq, cl = l15;
#pragma unroll
  for (int i=0;i<4;i++){
#pragma unroll
    for (int r=0;r<4;r++){
      int lrow = wr*64 + i*16 + rg*4 + r;
      float w = s_wv[lrow];
#pragma unroll
      for (int j=0;j<4;j++){
        int c = wc*64 + j*16 + cl;
        float v = (acc[i][j][r]*(1.f/16.f) + b2e[n0 + c]) * w;
        lds[lrow*128 + (c ^ ((lrow&7)<<4))] = fp8one(v);
      }
    }
  }
  __builtin_amdgcn_s_barrier();
#pragma unroll
  for (int w=0; w<4; ++w){
    int idx = w*256 + tid;
    int row = idx >> 3, u = idx & 7;
    int tk = s_tk[row];
    if (tk >= 0){
      int tok = tk & 0xffff, k = tk >> 30;
      *(i64x2*)(outb + ((size_t)(k*NT + tok))*DIM + n0 + u*16) =
          *(const i64x2*)(lds + row*128 + ((u*16) ^ ((row&7)<<4)));
    }
  }
}

// ---------------- combine: y = dec(outb[0][t]) + dec(outb[1][t]) ------------
__global__ __launch_bounds__(256) void combine_kernel(const unsigned char* __restrict__ outb,
                                                      float* __restrict__ y)
{
  int wid = threadIdx.x >> 6, lane = threadIdx.x & 63;
  int t = blockIdx.x*4 + wid;
  const uint4 a = *(const uint4*)(outb + (size_t)t*DIM + lane*16);
  const uint4 b = *(const uint4*)(outb + (size_t)(NT + t)*DIM + lane*16);
  float4* yo = (float4*)(y + (size_t)t*DIM + lane*16);
  unsigned ad[4] = {a.x, a.y, a.z, a.w};
  unsigned bd[4] = {b.x, b.y, b.z, b.w};
#pragma unroll
  for (int d=0; d<4; ++d){
    float4 o;
    o.x = fp8dec(ad[d] & 0xff)        + fp8dec(bd[d] & 0xff);
    o.y = fp8dec((ad[d]>>8) & 0xff)   + fp8dec((bd[d]>>8) & 0xff);
    o.z = fp8dec((ad[d]>>16) & 0xff)  + fp8dec((bd[d]>>16) & 0xff);
    o.w = fp8dec((ad[d]>>24) & 0xff)  + fp8dec((bd[d]>>24) & 0xff);
    yo[d] = o;
  }
}

// ---------------- launch ----------------------------------------------------
extern "C" void kernel_launch(void* const* d_in, const int* in_sizes, int n_in,
                              void* d_out, int out_size, void* d_ws, size_t ws_size,
                              hipStream_t stream)
{
  (void)in_sizes; (void)n_in; (void)ws_size; (void)out_size;
  const float* x  = (const float*)d_in[0];
  const float* rw = (const float*)d_in[1];
  const float* rb = (const float*)d_in[2];
  const float* w1 = (const float*)d_in[3];
  const float* b1 = (const float*)d_in[4];
  const float* w2 = (const float*)d_in[5];
  const float* b2 = (const float*)d_in[6];
  float* y = (float*)d_out;

  char* ws = (char*)d_ws;
  int*   counts = (int*)(ws + 0);
  int*   kept   = (int*)(ws + 64);
  float* imp    = (float*)(ws + 128);
  int*   padoff = (int*)(ws + 192);
  int*   list   = (int*)(ws + 0x1000);     // 512 KiB
  float* wtok   = (float*)(ws + 0x81000);  // 512 KiB
  int*   tki    = (int*)(ws + 0x101000);   // 128 KiB
  float* tkw    = (float*)(ws + 0x121000); // 128 KiB
  unsigned char* wt8  = (unsigned char*)(ws + 0x180000);   // 32 MiB (w1 then w2)
  unsigned char* hid8 = (unsigned char*)(ws + 0x2180000);  // 68 MiB (34816 x 2048)
  unsigned char* big  = (unsigned char*)(ws + 0x6580000);  // 32 MiB: x8 then outb
  unsigned char* x8   = big;                               // 16 MiB, dead after gemm1
  unsigned char* outb = big;                               // 32 MiB, overlays x8
  // total = 0x8580000 = 139.9 MiB

  hipMemsetAsync(ws, 0, 4096, stream);

  convx_kernel<<<NT*DIM/4/256, 256, 0, stream>>>(x, (unsigned*)x8);
  router_kernel<<<256, 256, 0, stream>>>(x, rw, rb, tki, tkw, counts, imp);
  build_lists_kernel<<<16, 1024, 0, stream>>>(tki, tkw, list, wtok, kept);
  finalize_kernel<<<1, 64, 0, stream>>>(counts, imp, kept, padoff, y + (size_t)NT*DIM);
  prepw_kernel<<<dim3(HID/64, DIM/64, NE), 256, 0, stream>>>(w1, wt8, DIM, HID, 16.f);
  gemm1_kernel<<<dim3(HID/128, CAP/128, NE), 256, 0, stream>>>(x8, wt8, b1, list, kept, padoff, hid8);
  // x8 now dead -> outb takes the region
  hipMemsetAsync(outb, 0, (size_t)2*NT*DIM, stream);
  prepw_kernel<<<dim3(DIM/64, HID/64, NE), 256, 0, stream>>>(w2, wt8, HID, DIM, 16.f);
  gemm2_kernel<<<dim3(DIM/128, CAP/128, NE), 256, 0, stream>>>(hid8, wt8, b2, list, wtok, kept, padoff, outb);
  combine_kernel<<<NT/4, 256, 0, stream>>>(outb, y);
}

// Round 5
// 426.142 us; speedup vs baseline: 3.2254x; 1.6122x over previous
//
#include <hip/hip_runtime.h>
#include <math.h>

#define NT   16384
#define DIM  1024
#define HID  2048
#define NE   16
#define CAP  8192
#define BK   64

typedef __attribute__((ext_vector_type(4))) short short4v;
typedef __attribute__((ext_vector_type(4))) float f32x4;
typedef long long i64;
typedef __attribute__((ext_vector_type(2))) long long i64x2;

__device__ __forceinline__ unsigned pk4fp8(float a, float b, float c, float d){
  int lo  = __builtin_amdgcn_cvt_pk_fp8_f32(a, b, 0, false);
  int all = __builtin_amdgcn_cvt_pk_fp8_f32(c, d, lo, true);
  return (unsigned)all;
}
__device__ __forceinline__ unsigned char fp8one(float a){
  return (unsigned char)(__builtin_amdgcn_cvt_pk_fp8_f32(a, a, 0, false) & 0xff);
}
// OCP e4m3fn decode
__device__ __forceinline__ float fp8dec(unsigned b){
  unsigned e = (b >> 3) & 15u, m = b & 7u;
  union { unsigned u; float f; } c;
  if (e) { c.u = ((b & 0x80u) << 24) | ((e + 120u) << 23) | (m << 20); return c.f; }
  float mag = (float)m * 0.001953125f;
  return (b & 0x80u) ? -mag : mag;
}

#define GLOAD16(g, l) __builtin_amdgcn_global_load_lds( \
    (const __attribute__((address_space(1))) void*)(g), \
    (__attribute__((address_space(3))) void*)(l), 16, 0, 0)

// dword permutation within a 64B k-chunk so lane kq's two i64 MFMA frags are
// one contiguous b128 at unit kq:  d -> kq(d)*4 + kk(d)*2 + pair(d)
__device__ __forceinline__ int permdw(int c4){
  return ((c4>>1)&3)*4 + (c4>>3)*2 + (c4&1);
}

// ---- fused: x -> fp8 (permuted) + router logits/softmax/top2 + importance --
__global__ __launch_bounds__(256) void convx_router_kernel(
    const float* __restrict__ x, const float* __restrict__ rw, const float* __restrict__ rb,
    unsigned* __restrict__ x8, int* __restrict__ tki, float* __restrict__ tkw,
    float* __restrict__ importance)
{
  __shared__ float sbuf[2][4][16];
  int tid = threadIdx.x;
  int lane = tid & 63, wid = tid >> 6;
  // router weights for this thread's 4 k-rows: 64 consecutive floats
  float W[64];
#pragma unroll
  for (int q=0;q<16;q++)
    *(float4*)(W + q*4) = ((const float4*)rw)[tid*16 + q];
  float rbv = rb[lane & 15];
  int chunk = tid >> 4, dd = permdw(tid & 15);
  float impAcc = 0.f;
  int b0 = lane&1, b1=(lane>>1)&1, b2=(lane>>2)&1, b3=(lane>>3)&1;
#pragma unroll 1
  for (int t=0;t<8;++t){
    int tok = blockIdx.x*8 + t;
    float4 xv = ((const float4*)x)[tok*256 + tid];
    x8[tok*256 + chunk*16 + dd] = pk4fp8(xv.x, xv.y, xv.z, xv.w);
    float p[16];
#pragma unroll
    for (int e=0;e<16;e++) p[e] = xv.x * W[e];
#pragma unroll
    for (int e=0;e<16;e++) p[e] += xv.y * W[16+e];
#pragma unroll
    for (int e=0;e<16;e++) p[e] += xv.z * W[32+e];
#pragma unroll
    for (int e=0;e<16;e++) p[e] += xv.w * W[48+e];
    // folded multi-value butterfly: lane L ends with sum for e = L&15
    float v8[8];
#pragma unroll
    for (int m=0;m<8;m++){
      float mine = b0 ? p[2*m+1] : p[2*m];
      float oth  = b0 ? p[2*m]   : p[2*m+1];
      v8[m] = mine + __shfl_xor(oth, 1, 64);
    }
    float v4a[4];
#pragma unroll
    for (int m=0;m<4;m++){
      float mine = b1 ? v8[2*m+1] : v8[2*m];
      float oth  = b1 ? v8[2*m]   : v8[2*m+1];
      v4a[m] = mine + __shfl_xor(oth, 2, 64);
    }
    float v2a[2];
#pragma unroll
    for (int m=0;m<2;m++){
      float mine = b2 ? v4a[2*m+1] : v4a[2*m];
      float oth  = b2 ? v4a[2*m]   : v4a[2*m+1];
      v2a[m] = mine + __shfl_xor(oth, 4, 64);
    }
    {
      float mine = b3 ? v2a[1] : v2a[0];
      float oth  = b3 ? v2a[0] : v2a[1];
      float v1 = mine + __shfl_xor(oth, 8, 64);
      v1 += __shfl_xor(v1, 16, 64);
      v1 += __shfl_xor(v1, 32, 64);
      if (lane < 16) sbuf[t&1][wid][lane] = v1;
    }
    __syncthreads();
    if (wid == 0){
      int e = lane & 15;
      float logit = sbuf[t&1][0][e] + sbuf[t&1][1][e] + sbuf[t&1][2][e] + sbuf[t&1][3][e] + rbv;
      float mx = logit;
#pragma unroll
      for (int d=1; d<16; d<<=1) mx = fmaxf(mx, __shfl_xor(mx, d, 64));
      float ex = __expf(logit - mx);
      float s = ex;
#pragma unroll
      for (int d=1; d<16; d<<=1) s += __shfl_xor(s, d, 64);
      float pe = ex / s;
      impAcc += pe;
      float v = pe; int idx = e;
#pragma unroll
      for (int d=1; d<16; d<<=1){
        float ov = __shfl_xor(v, d, 64);
        int   oi = __shfl_xor(idx, d, 64);
        bool bet = (ov > v) || (ov == v && oi < idx);
        v = bet ? ov : v; idx = bet ? oi : idx;
      }
      float vt1 = v; int i1 = idx;
      float pm = (e == i1) ? -1.f : pe;
      v = pm; idx = e;
#pragma unroll
      for (int d=1; d<16; d<<=1){
        float ov = __shfl_xor(v, d, 64);
        int   oi = __shfl_xor(idx, d, 64);
        bool bet = (ov > v) || (ov == v && oi < idx);
        v = bet ? ov : v; idx = bet ? oi : idx;
      }
      if (lane == 0){
        tki[2*tok] = i1; tki[2*tok+1] = idx;
        tkw[2*tok] = vt1; tkw[2*tok+1] = v;
      }
    }
  }
  if (wid == 0 && lane < 16) atomicAdd(&importance[lane], impAcc);
}

// ---------------- w [E][K][N] f32 -> wt8 [E][N][K] fp8 x16, permuted --------
__global__ __launch_bounds__(256) void prepw_kernel(const float* __restrict__ w,
                                                    unsigned char* __restrict__ wt8,
                                                    int K, int N, float scale){
  __shared__ float T[64][65];
  int e = blockIdx.z;
  int n0 = blockIdx.x*64, k0 = blockIdx.y*64;
  const float* we = w + (size_t)e*K*N;
  unsigned char* oe = wt8 + (size_t)e*K*N;
  int tid = threadIdx.x;
  int rr = tid >> 4, c4 = tid & 15;
#pragma unroll
  for (int p = 0; p < 4; ++p){
    int r = rr + p*16;
    float4 v = *(const float4*)(we + (size_t)(k0 + r)*N + n0 + c4*4);
    T[r][c4*4+0] = v.x*scale; T[r][c4*4+1] = v.y*scale;
    T[r][c4*4+2] = v.z*scale; T[r][c4*4+3] = v.w*scale;
  }
  __syncthreads();
  int dd = permdw(c4);
#pragma unroll
  for (int p = 0; p < 4; ++p){
    int n = rr + p*16;
    unsigned u = pk4fp8(T[c4*4+0][n], T[c4*4+1][n], T[c4*4+2][n], T[c4*4+3][n]);
    *(unsigned*)(oe + (size_t)(n0 + n)*K + k0 + dd*4) = u;
  }
}

// ---------------- per-expert ordered lists (ballot scan) --------------------
// wtok sign encodes top-k position: +w for k=0 (top-1), -w for k=1 (top-2)
__global__ __launch_bounds__(1024) void build_lists_kernel(
    const int* __restrict__ tki, const float* __restrict__ tkw,
    int* __restrict__ list, float* __restrict__ wtok, int* __restrict__ keptArr,
    int* __restrict__ counts)
{
  __shared__ int swsum[16];
  int e = blockIdx.x;
  int tid = threadIdx.x, wid = tid >> 6, lane = tid & 63;
  int base = 0;
  for (int c = 0; c < NT/1024; ++c){
    int t = c*1024 + tid;
    int i1 = tki[2*t], i2 = tki[2*t+1];
    bool m = (i1==e) || (i2==e);
    unsigned long long bal = __ballot(m);
    int inw = __popcll(bal & ((1ull << lane) - 1ull));
    if (lane == 0) swsum[wid] = __popcll(bal);
    __syncthreads();
    int pre = 0, tot = 0;
#pragma unroll
    for (int w = 0; w < 16; ++w){
      int v = swsum[w];
      tot += v;
      if (w < wid) pre += v;
    }
    int rank = base + pre + inw;
    if (m && rank < CAP){
      list[e*CAP + rank] = t;
      wtok[e*CAP + rank] = (i1==e) ? tkw[2*t] : -tkw[2*t+1];
    }
    base += tot;
    __syncthreads();
  }
  if (tid==0){ counts[e] = base; keptArr[e] = min(base, CAP); }
}

// ---------------- aux loss + padded (128) row offsets -----------------------
__global__ void finalize_kernel(const int* __restrict__ counts, const float* __restrict__ importance,
                                const int* __restrict__ keptArr, int* __restrict__ padOff,
                                float* __restrict__ auxOut)
{
  if (threadIdx.x == 0 && blockIdx.x == 0){
    float bal = 0.f, il = 0.f;
    int po = 0;
    padOff[0] = 0;
    for (int e=0;e<16;e++){
      float im = importance[e];
      float cf = (float)counts[e];
      bal += (im * (1.f/NT)) * (cf * (1.f/NT));
      il  += im*im;
      po  += ((keptArr[e] + 127) >> 7) << 7;
      padOff[e+1] = po;
    }
    auxOut[0] = bal * 16.f + il * (1.f/16.f);
  }
}

// ======== 128x128 fp8 GEMM, 4 waves, dbuf LDS, stage-early 2-phase ==========

#define STAGE(b) do{ \
  GLOAD16(pA0, lds + (b)*8192 + tid*16); \
  GLOAD16(pA1, lds + (b)*8192 + 4096 + tid*16); \
  GLOAD16(pB0, lds + 16384 + (b)*8192 + tid*16); \
  GLOAD16(pB1, lds + 16384 + (b)*8192 + 4096 + tid*16); \
  pA0 += BK; pA1 += BK; pB0 += BK; pB1 += BK; }while(0)

#define GEMM_FRAGS_AND_MFMA(At, Bt) \
  i64x2 bf[4], af[4]; \
  _Pragma("unroll") for (int j=0;j<4;j++) \
    bf[j] = *(const i64x2*)((Bt) + ((wc*64 + j*16 + l15)<<6) + rdsw); \
  _Pragma("unroll") for (int i=0;i<4;i++) \
    af[i] = *(const i64x2*)((At) + ((wr*64 + i*16 + l15)<<6) + rdsw);

// ---------------- GEMM1: hid8 = gelu(gather(x8) @ w1t8^T /16 + b1) ----------
__global__ __launch_bounds__(256, 3) void gemm1_kernel(
    const unsigned char* __restrict__ x8, const unsigned char* __restrict__ w1t8,
    const float* __restrict__ b1, const int* __restrict__ list,
    const int* __restrict__ keptArr, const int* __restrict__ padOff,
    unsigned char* __restrict__ hid8)
{
  __shared__ unsigned char lds[32768];  // A 2x8K @0, B 2x8K @16K; epilogue reuse
  int e = blockIdx.z;
  int kept = keptArr[e];
  int mt = blockIdx.y;
  if (mt*128 >= kept) return;
  int n0 = blockIdx.x * 128;

  const unsigned char* Wg = w1t8 + (size_t)e*DIM*HID;
  const int* lst = list + e*CAP;
  int tid = threadIdx.x;
  int lane = tid & 63, wv = tid >> 6;
  int wr = wv >> 1, wc = wv & 1;
  int l15 = lane & 15, kq = lane >> 4;
  int s2r = (l15 >> 1) & 3;
  int rdsw = (kq ^ s2r) << 4;

  int srow = tid >> 2, su = tid & 3;
  int r0 = srow, r1 = 64 + srow;
  int sx0 = (su ^ ((r0>>1)&3)) << 4, sx1 = (su ^ ((r1>>1)&3)) << 4;
  int t0 = lst[min(mt*128 + r0, kept-1)];
  int t1 = lst[min(mt*128 + r1, kept-1)];
  const unsigned char* pA0 = x8 + (size_t)t0*DIM + sx0;
  const unsigned char* pA1 = x8 + (size_t)t1*DIM + sx1;
  const unsigned char* pB0 = Wg + (size_t)(n0 + r0)*DIM + sx0;
  const unsigned char* pB1 = Wg + (size_t)(n0 + r1)*DIM + sx1;

  f32x4 acc[4][4];
#pragma unroll
  for (int i=0;i<4;i++)
#pragma unroll
    for (int j=0;j<4;j++) acc[i][j] = (f32x4){0.f,0.f,0.f,0.f};

  STAGE(0);
  asm volatile("s_waitcnt vmcnt(0)" ::: "memory");
  __builtin_amdgcn_s_barrier();

  const int nt = DIM/BK;   // 16
  for (int t = 0; t < nt; ++t){
    const unsigned char* At = lds + (t&1)*8192;
    const unsigned char* Bt = lds + 16384 + (t&1)*8192;
    GEMM_FRAGS_AND_MFMA(At, Bt)
    if (t+1 < nt) STAGE((t+1)&1);
#pragma unroll
    for (int i=0;i<4;i++)
#pragma unroll
      for (int j=0;j<4;j++){
        acc[i][j] = __builtin_amdgcn_mfma_f32_16x16x32_fp8_fp8(af[i][0], bf[j][0], acc[i][j], 0,0,0);
        acc[i][j] = __builtin_amdgcn_mfma_f32_16x16x32_fp8_fp8(af[i][1], bf[j][1], acc[i][j], 0,0,0);
      }
    if (t+1 < nt){
      asm volatile("s_waitcnt vmcnt(0)" ::: "memory");
      __builtin_amdgcn_s_barrier();
    }
  }

  // epilogue: bias+gelu -> fp8 (permuted cols), LDS repack, 16B stores
  __builtin_amdgcn_s_barrier();
  const float* b1e = b1 + (size_t)e*HID;
  int rg = kq, cl = l15;
#pragma unroll
  for (int i=0;i<4;i++){
#pragma unroll
    for (int j=0;j<4;j++){
      int c = wc*64 + j*16 + cl;
      float bias = b1e[n0 + c];
      int cc = c & 63, ch = c >> 6;
      int tb = ch*64 + ((cc>>3)&3)*16 + (cc>>5)*8 + (cc&7);
#pragma unroll
      for (int r=0;r<4;r++){
        int lrow = wr*64 + i*16 + rg*4 + r;
        float v = acc[i][j][r]*(1.f/16.f) + bias;
        float s = 1.f/(1.f + __expf(-1.702f*v));
        lds[lrow*128 + (tb ^ ((lrow&7)<<4))] = fp8one(v*s);
      }
    }
  }
  __builtin_amdgcn_s_barrier();
  size_t rowBase = (size_t)padOff[e] + (size_t)mt*128;
#pragma unroll
  for (int w=0; w<4; ++w){
    int idx = w*256 + tid;
    int row = idx >> 3, u = idx & 7;
    *(i64x2*)(hid8 + (rowBase + row)*HID + n0 + u*16) =
        *(const i64x2*)(lds + row*128 + ((u*16) ^ ((row&7)<<4)));
  }
}

// ---------------- GEMM2: outb[k][tok] = fp8( w * (hid8 @ w2t8^T /16 + b2) ) -
__global__ __launch_bounds__(256, 3) void gemm2_kernel(
    const unsigned char* __restrict__ hid8, const unsigned char* __restrict__ w2t8,
    const float* __restrict__ b2, const int* __restrict__ list,
    const float* __restrict__ wtok, const int* __restrict__ keptArr,
    const int* __restrict__ padOff, unsigned char* __restrict__ outb)
{
  __shared__ unsigned char lds[32768];
  __shared__ int   s_tk[128];
  __shared__ float s_wv[128];
  int e = blockIdx.z;
  int kept = keptArr[e];
  int mt = blockIdx.y;
  if (mt*128 >= kept) return;
  int n0 = blockIdx.x * 128;

  const unsigned char* Wg = w2t8 + (size_t)e*HID*DIM;
  const unsigned char* hb = hid8 + ((size_t)padOff[e] + (size_t)mt*128)*HID;
  const int*   lst = list + e*CAP;
  const float* wt  = wtok + e*CAP;
  int tid = threadIdx.x;
  int lane = tid & 63, wv = tid >> 6;
  int wr = wv >> 1, wc = wv & 1;
  int l15 = lane & 15, kq = lane >> 4;
  int s2r = (l15 >> 1) & 3;
  int rdsw = (kq ^ s2r) << 4;

  if (tid < 128){
    int m = mt*128 + tid;
    if (m < kept){
      float we = wt[m];
      s_tk[tid] = lst[m] | ((we < 0.f) ? (1<<30) : 0);
      s_wv[tid] = fabsf(we);
    } else { s_tk[tid] = -1; s_wv[tid] = 0.f; }
  }

  int srow = tid >> 2, su = tid & 3;
  int r0 = srow, r1 = 64 + srow;
  int sx0 = (su ^ ((r0>>1)&3)) << 4, sx1 = (su ^ ((r1>>1)&3)) << 4;
  const unsigned char* pA0 = hb + (size_t)r0*HID + sx0;
  const unsigned char* pA1 = hb + (size_t)r1*HID + sx1;
  const unsigned char* pB0 = Wg + (size_t)(n0 + r0)*HID + sx0;
  const unsigned char* pB1 = Wg + (size_t)(n0 + r1)*HID + sx1;

  f32x4 acc[4][4];
#pragma unroll
  for (int i=0;i<4;i++)
#pragma unroll
    for (int j=0;j<4;j++) acc[i][j] = (f32x4){0.f,0.f,0.f,0.f};

  STAGE(0);
  asm volatile("s_waitcnt vmcnt(0)" ::: "memory");
  __builtin_amdgcn_s_barrier();

  const int nt = HID/BK;   // 32
  for (int t = 0; t < nt; ++t){
    const unsigned char* At = lds + (t&1)*8192;
    const unsigned char* Bt = lds + 16384 + (t&1)*8192;
    GEMM_FRAGS_AND_MFMA(At, Bt)
    if (t+1 < nt) STAGE((t+1)&1);
#pragma unroll
    for (int i=0;i<4;i++)
#pragma unroll
      for (int j=0;j<4;j++){
        acc[i][j] = __builtin_amdgcn_mfma_f32_16x16x32_fp8_fp8(af[i][0], bf[j][0], acc[i][j], 0,0,0);
        acc[i][j] = __builtin_amdgcn_mfma_f32_16x16x32_fp8_fp8(af[i][1], bf[j][1], acc[i][j], 0,0,0);
      }
    if (t+1 < nt){
      asm volatile("s_waitcnt vmcnt(0)" ::: "memory");
      __builtin_amdgcn_s_barrier();
    }
  }

  // epilogue: w*(acc/16 + b2) -> fp8, repack via LDS, 16B stores to outb
  __builtin_amdgcn_s_barrier();
  const float* b2e = b2 + (size_t)e*DIM;
  int rg = kq, cl = l15;
#pragma unroll
  for (int i=0;i<4;i++){
#pragma unroll
    for (int r=0;r<4;r++){
      int lrow = wr*64 + i*16 + rg*4 + r;
      float w = s_wv[lrow];
#pragma unroll
      for (int j=0;j<4;j++){
        int c = wc*64 + j*16 + cl;
        float v = (acc[i][j][r]*(1.f/16.f) + b2e[n0 + c]) * w;
        lds[lrow*128 + (c ^ ((lrow&7)<<4))] = fp8one(v);
      }
    }
  }
  __builtin_amdgcn_s_barrier();
#pragma unroll
  for (int w=0; w<4; ++w){
    int idx = w*256 + tid;
    int row = idx >> 3, u = idx & 7;
    int tk = s_tk[row];
    if (tk >= 0){
      int tok = tk & 0xffff, k = tk >> 30;
      *(i64x2*)(outb + ((size_t)(k*NT + tok))*DIM + n0 + u*16) =
          *(const i64x2*)(lds + row*128 + ((u*16) ^ ((row&7)<<4)));
    }
  }
}

// ---------------- combine: y = dec(outb[0][t]) + dec(outb[1][t]) ------------
__global__ __launch_bounds__(256) void combine_kernel(const unsigned char* __restrict__ outb,
                                                      float* __restrict__ y)
{
  int wid = threadIdx.x >> 6, lane = threadIdx.x & 63;
  int t = blockIdx.x*4 + wid;
  const uint4 a = *(const uint4*)(outb + (size_t)t*DIM + lane*16);
  const uint4 b = *(const uint4*)(outb + (size_t)(NT + t)*DIM + lane*16);
  float4* yo = (float4*)(y + (size_t)t*DIM + lane*16);
  unsigned ad[4] = {a.x, a.y, a.z, a.w};
  unsigned bd[4] = {b.x, b.y, b.z, b.w};
#pragma unroll
  for (int d=0; d<4; ++d){
    float4 o;
    o.x = fp8dec(ad[d] & 0xff)        + fp8dec(bd[d] & 0xff);
    o.y = fp8dec((ad[d]>>8) & 0xff)   + fp8dec((bd[d]>>8) & 0xff);
    o.z = fp8dec((ad[d]>>16) & 0xff)  + fp8dec((bd[d]>>16) & 0xff);
    o.w = fp8dec((ad[d]>>24) & 0xff)  + fp8dec((bd[d]>>24) & 0xff);
    yo[d] = o;
  }
}

// ---------------- launch ----------------------------------------------------
extern "C" void kernel_launch(void* const* d_in, const int* in_sizes, int n_in,
                              void* d_out, int out_size, void* d_ws, size_t ws_size,
                              hipStream_t stream)
{
  (void)in_sizes; (void)n_in; (void)ws_size; (void)out_size;
  const float* x  = (const float*)d_in[0];
  const float* rw = (const float*)d_in[1];
  const float* rb = (const float*)d_in[2];
  const float* w1 = (const float*)d_in[3];
  const float* b1 = (const float*)d_in[4];
  const float* w2 = (const float*)d_in[5];
  const float* b2 = (const float*)d_in[6];
  float* y = (float*)d_out;

  char* ws = (char*)d_ws;
  int*   counts = (int*)(ws + 0);
  int*   kept   = (int*)(ws + 64);
  float* imp    = (float*)(ws + 128);
  int*   padoff = (int*)(ws + 192);
  int*   list   = (int*)(ws + 0x1000);     // 512 KiB
  float* wtok   = (float*)(ws + 0x81000);  // 512 KiB
  int*   tki    = (int*)(ws + 0x101000);   // 128 KiB
  float* tkw    = (float*)(ws + 0x121000); // 128 KiB
  unsigned char* wt8  = (unsigned char*)(ws + 0x180000);   // 32 MiB (w1 then w2)
  unsigned char* hid8 = (unsigned char*)(ws + 0x2180000);  // 68 MiB (34816 x 2048)
  unsigned char* big  = (unsigned char*)(ws + 0x6580000);  // 32 MiB: x8 then outb
  unsigned char* x8   = big;                               // 16 MiB, dead after gemm1
  unsigned char* outb = big;                               // 32 MiB, overlays x8
  // total = 0x8580000 = 139.9 MiB

  hipMemsetAsync(ws, 0, 4096, stream);

  convx_router_kernel<<<NT/8, 256, 0, stream>>>(x, rw, rb, (unsigned*)x8, tki, tkw, imp);
  build_lists_kernel<<<16, 1024, 0, stream>>>(tki, tkw, list, wtok, kept, counts);
  finalize_kernel<<<1, 64, 0, stream>>>(counts, imp, kept, padoff, y + (size_t)NT*DIM);
  prepw_kernel<<<dim3(HID/64, DIM/64, NE), 256, 0, stream>>>(w1, wt8, DIM, HID, 16.f);
  gemm1_kernel<<<dim3(HID/128, CAP/128, NE), 256, 0, stream>>>(x8, wt8, b1, list, kept, padoff, hid8);
  // x8 now dead -> outb takes the region
  hipMemsetAsync(outb, 0, (size_t)2*NT*DIM, stream);
  prepw_kernel<<<dim3(DIM/64, HID/64, NE), 256, 0, stream>>>(w2, wt8, HID, DIM, 16.f);
  gemm2_kernel<<<dim3(DIM/128, CAP/128, NE), 256, 0, stream>>>(hid8, wt8, b2, list, wtok, kept, padoff, outb);
  combine_kernel<<<NT/4, 256, 0, stream>>>(outb, y);
}

// Round 6
// 386.776 us; speedup vs baseline: 3.5537x; 1.1018x over previous
//
#include <hip/hip_runtime.h>
#include <math.h>

#define NT   16384
#define DIM  1024
#define HID  2048
#define NE   16
#define CAP  8192

typedef __attribute__((ext_vector_type(4))) float f32x4;
typedef __attribute__((ext_vector_type(4))) int   i32x4;
typedef __attribute__((ext_vector_type(8))) int   i32x8;
typedef __attribute__((ext_vector_type(2))) long long i64x2;

__device__ __forceinline__ unsigned pk4fp8(float a, float b, float c, float d){
  int lo  = __builtin_amdgcn_cvt_pk_fp8_f32(a, b, 0, false);
  int all = __builtin_amdgcn_cvt_pk_fp8_f32(c, d, lo, true);
  return (unsigned)all;
}
__device__ __forceinline__ unsigned char fp8one(float a){
  return (unsigned char)(__builtin_amdgcn_cvt_pk_fp8_f32(a, a, 0, false) & 0xff);
}
// OCP e4m3fn decode
__device__ __forceinline__ float fp8dec(unsigned b){
  unsigned e = (b >> 3) & 15u, m = b & 7u;
  union { unsigned u; float f; } c;
  if (e) { c.u = ((b & 0x80u) << 24) | ((e + 120u) << 23) | (m << 20); return c.f; }
  float mag = (float)m * 0.001953125f;
  return (b & 0x80u) ? -mag : mag;
}

#define GLOAD16(g, l) __builtin_amdgcn_global_load_lds( \
    (const __attribute__((address_space(1))) void*)(g), \
    (__attribute__((address_space(3))) void*)(l), 16, 0, 0)

// ---- fused: x -> fp8 (plain rows) + router logits/softmax/top2 + importance
__global__ __launch_bounds__(256) void convx_router_kernel(
    const float* __restrict__ x, const float* __restrict__ rw, const float* __restrict__ rb,
    unsigned* __restrict__ x8, int* __restrict__ tki, float* __restrict__ tkw,
    float* __restrict__ importance)
{
  __shared__ float sbuf[2][4][16];
  int tid = threadIdx.x;
  int lane = tid & 63, wid = tid >> 6;
  float W[64];
#pragma unroll
  for (int q=0;q<16;q++)
    *(float4*)(W + q*4) = ((const float4*)rw)[tid*16 + q];
  float rbv = rb[lane & 15];
  float impAcc = 0.f;
  int b0 = lane&1, b1=(lane>>1)&1, b2=(lane>>2)&1, b3=(lane>>3)&1;
#pragma unroll 1
  for (int t=0;t<8;++t){
    int tok = blockIdx.x*8 + t;
    float4 xv = ((const float4*)x)[tok*256 + tid];
    x8[tok*256 + tid] = pk4fp8(xv.x, xv.y, xv.z, xv.w);
    float p[16];
#pragma unroll
    for (int e=0;e<16;e++) p[e] = xv.x * W[e];
#pragma unroll
    for (int e=0;e<16;e++) p[e] += xv.y * W[16+e];
#pragma unroll
    for (int e=0;e<16;e++) p[e] += xv.z * W[32+e];
#pragma unroll
    for (int e=0;e<16;e++) p[e] += xv.w * W[48+e];
    float v8[8];
#pragma unroll
    for (int m=0;m<8;m++){
      float mine = b0 ? p[2*m+1] : p[2*m];
      float oth  = b0 ? p[2*m]   : p[2*m+1];
      v8[m] = mine + __shfl_xor(oth, 1, 64);
    }
    float v4a[4];
#pragma unroll
    for (int m=0;m<4;m++){
      float mine = b1 ? v8[2*m+1] : v8[2*m];
      float oth  = b1 ? v8[2*m]   : v8[2*m+1];
      v4a[m] = mine + __shfl_xor(oth, 2, 64);
    }
    float v2a[2];
#pragma unroll
    for (int m=0;m<2;m++){
      float mine = b2 ? v4a[2*m+1] : v4a[2*m];
      float oth  = b2 ? v4a[2*m]   : v4a[2*m+1];
      v2a[m] = mine + __shfl_xor(oth, 4, 64);
    }
    {
      float mine = b3 ? v2a[1] : v2a[0];
      float oth  = b3 ? v2a[0] : v2a[1];
      float v1 = mine + __shfl_xor(oth, 8, 64);
      v1 += __shfl_xor(v1, 16, 64);
      v1 += __shfl_xor(v1, 32, 64);
      if (lane < 16) sbuf[t&1][wid][lane] = v1;
    }
    __syncthreads();
    if (wid == 0){
      int e = lane & 15;
      float logit = sbuf[t&1][0][e] + sbuf[t&1][1][e] + sbuf[t&1][2][e] + sbuf[t&1][3][e] + rbv;
      float mx = logit;
#pragma unroll
      for (int d=1; d<16; d<<=1) mx = fmaxf(mx, __shfl_xor(mx, d, 64));
      float ex = __expf(logit - mx);
      float s = ex;
#pragma unroll
      for (int d=1; d<16; d<<=1) s += __shfl_xor(s, d, 64);
      float pe = ex / s;
      impAcc += pe;
      float v = pe; int idx = e;
#pragma unroll
      for (int d=1; d<16; d<<=1){
        float ov = __shfl_xor(v, d, 64);
        int   oi = __shfl_xor(idx, d, 64);
        bool bet = (ov > v) || (ov == v && oi < idx);
        v = bet ? ov : v; idx = bet ? oi : idx;
      }
      float vt1 = v; int i1 = idx;
      float pm = (e == i1) ? -1.f : pe;
      v = pm; idx = e;
#pragma unroll
      for (int d=1; d<16; d<<=1){
        float ov = __shfl_xor(v, d, 64);
        int   oi = __shfl_xor(idx, d, 64);
        bool bet = (ov > v) || (ov == v && oi < idx);
        v = bet ? ov : v; idx = bet ? oi : idx;
      }
      if (lane == 0){
        tki[2*tok] = i1; tki[2*tok+1] = idx;
        tkw[2*tok] = vt1; tkw[2*tok+1] = v;
      }
    }
  }
  if (wid == 0 && lane < 16) atomicAdd(&importance[lane], impAcc);
}

// ---------------- w [E][K][N] f32 -> wt8 [E][N][K] fp8 x16 (plain) ----------
__global__ __launch_bounds__(256) void prepw_kernel(const float* __restrict__ w,
                                                    unsigned char* __restrict__ wt8,
                                                    int K, int N, float scale){
  __shared__ float T[64][65];
  int e = blockIdx.z;
  int n0 = blockIdx.x*64, k0 = blockIdx.y*64;
  const float* we = w + (size_t)e*K*N;
  unsigned char* oe = wt8 + (size_t)e*K*N;
  int tid = threadIdx.x;
  int rr = tid >> 4, c4 = tid & 15;
#pragma unroll
  for (int p = 0; p < 4; ++p){
    int r = rr + p*16;
    float4 v = *(const float4*)(we + (size_t)(k0 + r)*N + n0 + c4*4);
    T[r][c4*4+0] = v.x*scale; T[r][c4*4+1] = v.y*scale;
    T[r][c4*4+2] = v.z*scale; T[r][c4*4+3] = v.w*scale;
  }
  __syncthreads();
#pragma unroll
  for (int p = 0; p < 4; ++p){
    int n = rr + p*16;
    unsigned u = pk4fp8(T[c4*4+0][n], T[c4*4+1][n], T[c4*4+2][n], T[c4*4+3][n]);
    *(unsigned*)(oe + (size_t)(n0 + n)*K + k0 + c4*4) = u;
  }
}

// ---------------- per-expert ordered lists (ballot scan) --------------------
__global__ __launch_bounds__(1024) void build_lists_kernel(
    const int* __restrict__ tki, const float* __restrict__ tkw,
    int* __restrict__ list, float* __restrict__ wtok, int* __restrict__ keptArr,
    int* __restrict__ counts)
{
  __shared__ int swsum[16];
  int e = blockIdx.x;
  int tid = threadIdx.x, wid = tid >> 6, lane = tid & 63;
  int base = 0;
  for (int c = 0; c < NT/1024; ++c){
    int t = c*1024 + tid;
    int i1 = tki[2*t], i2 = tki[2*t+1];
    bool m = (i1==e) || (i2==e);
    unsigned long long bal = __ballot(m);
    int inw = __popcll(bal & ((1ull << lane) - 1ull));
    if (lane == 0) swsum[wid] = __popcll(bal);
    __syncthreads();
    int pre = 0, tot = 0;
#pragma unroll
    for (int w = 0; w < 16; ++w){
      int v = swsum[w];
      tot += v;
      if (w < wid) pre += v;
    }
    int rank = base + pre + inw;
    if (m && rank < CAP){
      list[e*CAP + rank] = t;
      wtok[e*CAP + rank] = (i1==e) ? tkw[2*t] : -tkw[2*t+1];
    }
    base += tot;
    __syncthreads();
  }
  if (tid==0){ counts[e] = base; keptArr[e] = min(base, CAP); }
}

// ---------------- aux loss + padded (128) row offsets -----------------------
__global__ void finalize_kernel(const int* __restrict__ counts, const float* __restrict__ importance,
                                const int* __restrict__ keptArr, int* __restrict__ padOff,
                                float* __restrict__ auxOut)
{
  if (threadIdx.x == 0 && blockIdx.x == 0){
    float bal = 0.f, il = 0.f;
    int po = 0;
    padOff[0] = 0;
    for (int e=0;e<16;e++){
      float im = importance[e];
      float cf = (float)counts[e];
      bal += (im * (1.f/NT)) * (cf * (1.f/NT));
      il  += im*im;
      po  += ((keptArr[e] + 127) >> 7) << 7;
      padOff[e+1] = po;
    }
    auxOut[0] = bal * 16.f + il * (1.f/16.f);
  }
}

// ===== 128x128 MX-fp8 GEMM (16x16x128 scaled MFMA), single-buf 2-barrier ====
// LDS tile layout: per 16-row block (2KB), granule (r, u) [u = 16B unit 0..7]
// at (u&1)*1024 + r*64 + (u>>1)*16  -> each wave b128 frag read tiles 1KB
// exactly once (0 bank conflicts). Staged via per-lane SOURCE addressing with
// linear gload dest (rule 21). Scales: A x1 (127), B x2^-4 (123).

#define SETUP_PTRS(SRC_A_EXPR, SRC_B_EXPR, LDK) \
  const unsigned char* pA[4]; const unsigned char* pB[4]; \
  _Pragma("unroll") \
  for (int l=0; l<4; ++l){ \
    int g = l*256 + tid; \
    int mb = g>>7, w = g&127; \
    int u = ((w&3)<<1) | ((w>>6)&1); \
    int row = mb*16 + ((w>>2)&15); \
    int koff = u*16; \
    pA[l] = (SRC_A_EXPR) + koff; \
    pB[l] = (SRC_B_EXPR) + koff; \
  }

#define STAGE8() do{ \
  GLOAD16(pA[0], lds + tid*16);          GLOAD16(pA[1], lds + 4096 + tid*16); \
  GLOAD16(pA[2], lds + 8192 + tid*16);   GLOAD16(pA[3], lds + 12288 + tid*16); \
  GLOAD16(pB[0], lds + 16384 + tid*16);  GLOAD16(pB[1], lds + 20480 + tid*16); \
  GLOAD16(pB[2], lds + 24576 + tid*16);  GLOAD16(pB[3], lds + 28672 + tid*16); \
  pA[0]+=128; pA[1]+=128; pA[2]+=128; pA[3]+=128; \
  pB[0]+=128; pB[1]+=128; pB[2]+=128; pB[3]+=128; }while(0)

#define KLOOP(NT_) \
  for (int t = 0; t < (NT_); ++t){ \
    STAGE8(); \
    asm volatile("s_waitcnt vmcnt(0)" ::: "memory"); \
    __builtin_amdgcn_s_barrier(); \
    i32x8 b[4]; \
    _Pragma("unroll") \
    for (int nj=0; nj<4; ++nj){ \
      const unsigned char* bb = lds + 16384 + (wc*4+nj)*2048 + l15*64 + kq*16; \
      i32x4 lo = *(const i32x4*)bb; \
      i32x4 hi = *(const i32x4*)(bb + 1024); \
      b[nj] = __builtin_shufflevector(lo, hi, 0,1,2,3,4,5,6,7); \
    } \
    __builtin_amdgcn_s_setprio(1); \
    _Pragma("unroll") \
    for (int mi=0; mi<4; ++mi){ \
      const unsigned char* ab = lds + (wr*4+mi)*2048 + l15*64 + kq*16; \
      i32x4 lo = *(const i32x4*)ab; \
      i32x4 hi = *(const i32x4*)(ab + 1024); \
      i32x8 a = __builtin_shufflevector(lo, hi, 0,1,2,3,4,5,6,7); \
      _Pragma("unroll") \
      for (int nj=0; nj<4; ++nj) \
        acc[mi][nj] = __builtin_amdgcn_mfma_scale_f32_16x16x128_f8f6f4( \
            a, b[nj], acc[mi][nj], 0, 0, 0, 127, 0, 123); \
    } \
    __builtin_amdgcn_s_setprio(0); \
    __builtin_amdgcn_s_barrier(); \
  }

// ---------------- GEMM1: hid8 = gelu(gather(x8) @ w1t8^T + b1) --------------
__global__ __launch_bounds__(256, 3) void gemm1_kernel(
    const unsigned char* __restrict__ x8, const unsigned char* __restrict__ w1t8,
    const float* __restrict__ b1, const int* __restrict__ list,
    const int* __restrict__ keptArr, const int* __restrict__ padOff,
    unsigned char* __restrict__ hid8)
{
  __shared__ unsigned char lds[32768];   // A 16K @0, B 16K @16K; epilogue reuse
  int e = blockIdx.z;
  int kept = keptArr[e];
  int mt = blockIdx.y;
  if (mt*128 >= kept) return;
  int n0 = blockIdx.x * 128;

  const unsigned char* Wg = w1t8 + (size_t)e*DIM*HID;
  const int* lst = list + e*CAP;
  int tid = threadIdx.x;
  int lane = tid & 63, wv = tid >> 6;
  int wr = wv >> 1, wc = wv & 1;
  int l15 = lane & 15, kq = lane >> 4;

  SETUP_PTRS(x8 + (size_t)lst[min(mt*128 + row, kept-1)]*DIM,
             Wg + (size_t)(n0 + row)*DIM, DIM)

  f32x4 acc[4][4];
#pragma unroll
  for (int i=0;i<4;i++)
#pragma unroll
    for (int j=0;j<4;j++) acc[i][j] = (f32x4){0.f,0.f,0.f,0.f};

  KLOOP(DIM/128)   // 8

  // epilogue: bias+gelu -> fp8, LDS repack, coalesced 16B stores
  const float* b1e = b1 + (size_t)e*HID;
#pragma unroll
  for (int i=0;i<4;i++){
#pragma unroll
    for (int j=0;j<4;j++){
      int c = wc*64 + j*16 + l15;
      float bias = b1e[n0 + c];
#pragma unroll
      for (int r=0;r<4;r++){
        int lrow = wr*64 + i*16 + kq*4 + r;
        float v = acc[i][j][r] + bias;
        float s = 1.f/(1.f + __expf(-1.702f*v));   // sigmoid-approx GELU
        lds[lrow*128 + (c ^ ((lrow&7)<<4))] = fp8one(v*s);
      }
    }
  }
  __builtin_amdgcn_s_barrier();
  size_t rowBase = (size_t)padOff[e] + (size_t)mt*128;
#pragma unroll
  for (int w=0; w<4; ++w){
    int idx = w*256 + tid;
    int row = idx >> 3, u = idx & 7;
    *(i64x2*)(hid8 + (rowBase + row)*HID + n0 + u*16) =
        *(const i64x2*)(lds + row*128 + ((u*16) ^ ((row&7)<<4)));
  }
}

// ---------------- GEMM2: outb[k][tok] = fp8( w * (hid8 @ w2t8^T + b2) ) -----
__global__ __launch_bounds__(256, 3) void gemm2_kernel(
    const unsigned char* __restrict__ hid8, const unsigned char* __restrict__ w2t8,
    const float* __restrict__ b2, const int* __restrict__ list,
    const float* __restrict__ wtok, const int* __restrict__ keptArr,
    const int* __restrict__ padOff, unsigned char* __restrict__ outb)
{
  __shared__ unsigned char lds[32768];
  __shared__ int   s_tk[128];
  __shared__ float s_wv[128];
  int e = blockIdx.z;
  int kept = keptArr[e];
  int mt = blockIdx.y;
  if (mt*128 >= kept) return;
  int n0 = blockIdx.x * 128;

  const unsigned char* Wg = w2t8 + (size_t)e*HID*DIM;
  const unsigned char* hb = hid8 + ((size_t)padOff[e] + (size_t)mt*128)*HID;
  const int*   lst = list + e*CAP;
  const float* wt  = wtok + e*CAP;
  int tid = threadIdx.x;
  int lane = tid & 63, wv = tid >> 6;
  int wr = wv >> 1, wc = wv & 1;
  int l15 = lane & 15, kq = lane >> 4;

  if (tid < 128){
    int m = mt*128 + tid;
    if (m < kept){
      float we = wt[m];
      s_tk[tid] = lst[m] | ((we < 0.f) ? (1<<30) : 0);
      s_wv[tid] = fabsf(we);
    } else { s_tk[tid] = -1; s_wv[tid] = 0.f; }
  }

  SETUP_PTRS(hb + (size_t)row*HID,
             Wg + (size_t)(n0 + row)*HID, HID)

  f32x4 acc[4][4];
#pragma unroll
  for (int i=0;i<4;i++)
#pragma unroll
    for (int j=0;j<4;j++) acc[i][j] = (f32x4){0.f,0.f,0.f,0.f};

  KLOOP(HID/128)   // 16

  // epilogue: w*(acc + b2) -> fp8, repack via LDS, 16B stores to outb
  const float* b2e = b2 + (size_t)e*DIM;
#pragma unroll
  for (int i=0;i<4;i++){
#pragma unroll
    for (int r=0;r<4;r++){
      int lrow = wr*64 + i*16 + kq*4 + r;
      float w = s_wv[lrow];
#pragma unroll
      for (int j=0;j<4;j++){
        int c = wc*64 + j*16 + l15;
        float v = (acc[i][j][r] + b2e[n0 + c]) * w;
        lds[lrow*128 + (c ^ ((lrow&7)<<4))] = fp8one(v);
      }
    }
  }
  __builtin_amdgcn_s_barrier();
#pragma unroll
  for (int w=0; w<4; ++w){
    int idx = w*256 + tid;
    int row = idx >> 3, u = idx & 7;
    int tk = s_tk[row];
    if (tk >= 0){
      int tok = tk & 0xffff, k = tk >> 30;
      *(i64x2*)(outb + ((size_t)(k*NT + tok))*DIM + n0 + u*16) =
          *(const i64x2*)(lds + row*128 + ((u*16) ^ ((row&7)<<4)));
    }
  }
}

// ---------------- combine: y = dec(outb[0][t]) + dec(outb[1][t]) ------------
__global__ __launch_bounds__(256) void combine_kernel(const unsigned char* __restrict__ outb,
                                                      float* __restrict__ y)
{
  int wid = threadIdx.x >> 6, lane = threadIdx.x & 63;
  int t = blockIdx.x*4 + wid;
  const uint4 a = *(const uint4*)(outb + (size_t)t*DIM + lane*16);
  const uint4 b = *(const uint4*)(outb + (size_t)(NT + t)*DIM + lane*16);
  float4* yo = (float4*)(y + (size_t)t*DIM + lane*16);
  unsigned ad[4] = {a.x, a.y, a.z, a.w};
  unsigned bd[4] = {b.x, b.y, b.z, b.w};
#pragma unroll
  for (int d=0; d<4; ++d){
    float4 o;
    o.x = fp8dec(ad[d] & 0xff)        + fp8dec(bd[d] & 0xff);
    o.y = fp8dec((ad[d]>>8) & 0xff)   + fp8dec((bd[d]>>8) & 0xff);
    o.z = fp8dec((ad[d]>>16) & 0xff)  + fp8dec((bd[d]>>16) & 0xff);
    o.w = fp8dec((ad[d]>>24) & 0xff)  + fp8dec((bd[d]>>24) & 0xff);
    yo[d] = o;
  }
}

// ---------------- launch ----------------------------------------------------
extern "C" void kernel_launch(void* const* d_in, const int* in_sizes, int n_in,
                              void* d_out, int out_size, void* d_ws, size_t ws_size,
                              hipStream_t stream)
{
  (void)in_sizes; (void)n_in; (void)ws_size; (void)out_size;
  const float* x  = (const float*)d_in[0];
  const float* rw = (const float*)d_in[1];
  const float* rb = (const float*)d_in[2];
  const float* w1 = (const float*)d_in[3];
  const float* b1 = (const float*)d_in[4];
  const float* w2 = (const float*)d_in[5];
  const float* b2 = (const float*)d_in[6];
  float* y = (float*)d_out;

  char* ws = (char*)d_ws;
  int*   counts = (int*)(ws + 0);
  int*   kept   = (int*)(ws + 64);
  float* imp    = (float*)(ws + 128);
  int*   padoff = (int*)(ws + 192);
  int*   list   = (int*)(ws + 0x1000);     // 512 KiB
  float* wtok   = (float*)(ws + 0x81000);  // 512 KiB
  int*   tki    = (int*)(ws + 0x101000);   // 128 KiB
  float* tkw    = (float*)(ws + 0x121000); // 128 KiB
  unsigned char* wt8  = (unsigned char*)(ws + 0x180000);   // 32 MiB (w1 then w2)
  unsigned char* hid8 = (unsigned char*)(ws + 0x2180000);  // 68 MiB (34816 x 2048)
  unsigned char* big  = (unsigned char*)(ws + 0x6580000);  // 32 MiB: x8 then outb
  unsigned char* x8   = big;                               // 16 MiB, dead after gemm1
  unsigned char* outb = big;                               // 32 MiB, overlays x8
  // total = 0x8580000 = 139.9 MiB

  hipMemsetAsync(ws, 0, 4096, stream);

  convx_router_kernel<<<NT/8, 256, 0, stream>>>(x, rw, rb, (unsigned*)x8, tki, tkw, imp);
  build_lists_kernel<<<16, 1024, 0, stream>>>(tki, tkw, list, wtok, kept, counts);
  finalize_kernel<<<1, 64, 0, stream>>>(counts, imp, kept, padoff, y + (size_t)NT*DIM);
  prepw_kernel<<<dim3(HID/64, DIM/64, NE), 256, 0, stream>>>(w1, wt8, DIM, HID, 16.f);
  gemm1_kernel<<<dim3(HID/128, CAP/128, NE), 256, 0, stream>>>(x8, wt8, b1, list, kept, padoff, hid8);
  // x8 now dead -> outb takes the region
  hipMemsetAsync(outb, 0, (size_t)2*NT*DIM, stream);
  prepw_kernel<<<dim3(DIM/64, HID/64, NE), 256, 0, stream>>>(w2, wt8, HID, DIM, 16.f);
  gemm2_kernel<<<dim3(DIM/128, CAP/128, NE), 256, 0, stream>>>(hid8, wt8, b2, list, wtok, kept, padoff, outb);
  combine_kernel<<<NT/4, 256, 0, stream>>>(outb, y);
}